// Round 6
// baseline (701.834 us; speedup 1.0000x reference)
//
#include <hip/hip_runtime.h>
#include <hip/hip_bf16.h>

#define GG 128
#define SLOPE 0.01f
#define CHUNK 8192
#define NPB 64   // nodes per block in k_step
#define NREP 64  // accumulator replicas (atomic contention striping)

// wcat element offsets (f32 staged weights)
#define OFF_Wm   0
#define OFF_bm   3072
#define OFF_Wa   3168
#define OFF_ba   12384
#define OFF_Wg   12480
#define OFF_bg   12576
#define OFF_Wf   12592
#define OFF_bf   15664
#define OFF_Wt   15760
#define OFF_bt   21904
#define OFF_Wa1  22000
#define OFF_ba1  22032
#define WCAT_N   22048

__device__ __forceinline__ float lrelu(float v) { return v > 0.f ? v : SLOPE * v; }

__device__ __forceinline__ float ldf(const void* p, int i, int isf) {
    if (isf) return ((const float*)p)[i];
    return __bfloat162float(((const __hip_bfloat16*)p)[i]);
}
__device__ __forceinline__ void stf(void* p, int i, float v, int isf) {
    if (isf) ((float*)p)[i] = v;
    else ((__hip_bfloat16*)p)[i] = __float2bfloat16(v);
}

// bf16-pair unpack from u32 (bit ops only)
__device__ __forceinline__ float bfLo(unsigned u) { return __uint_as_float(u << 16); }
__device__ __forceinline__ float bfHi(unsigned u) { return __uint_as_float(u & 0xFFFF0000u); }

// ---------------- dtype detection ----------------
__global__ void k_detect(const unsigned short* __restrict__ w, int n, int* __restrict__ flag) {
    __shared__ int bad;
    if (threadIdx.x == 0) bad = 0;
    __syncthreads();
    for (int t = threadIdx.x; t < n; t += 256) {
        unsigned short u = w[t];
        int e = (u >> 7) & 0xFF;
        if (e >= 141) bad = 1;  // benign same-value race
    }
    __syncthreads();
    if (threadIdx.x == 0) { flag[0] = bad; flag[32] = 1; }
}

// ---------------- one-shot weight staging to f32 ----------------
struct CvtArgs {
    const void* p[12];
    int off[12];
    int n[12];
};
__global__ void k_cvt_all(CvtArgs a, float* __restrict__ dst, const int* __restrict__ dtf) {
    int isf = *dtf;
    int seg = blockIdx.y;
    int i = blockIdx.x * 256 + threadIdx.x;
    if (i < a.n[seg]) dst[a.off[seg] + i] = ldf(a.p[seg], i, isf);
}

// ---------------- xgw init for step 0: xg = 0 -> xgw = ba0 broadcast ----------------
__global__ void k_xgw0(const void* __restrict__ ba0, float* __restrict__ xgw,
                       const int* __restrict__ dtf) {
    int isf = *dtf;
    int idx = blockIdx.x * 256 + threadIdx.x;  // 0..GG*32-1
    xgw[idx] = ldf(ba0, idx & 31, isf);
}

// ---------------- embed + step-0 message (fused; m node-major) ----------------
__global__ void k_embed_msg(const void* __restrict__ nf, const void* __restrict__ We,
                            const void* __restrict__ be,
                            const float* __restrict__ Wm0, const float* __restrict__ bm0,
                            float* __restrict__ x, __hip_bfloat16* __restrict__ m, int N,
                            const int* __restrict__ dtf) {
    __shared__ float WL[1024];
    __shared__ float WeL[32], beL[32], bmL[32];
    __shared__ float xs[8][32];
    int isf = *dtf;
    int tid = threadIdx.x;
    for (int t = tid; t < 1024; t += 256) WL[t] = Wm0[t];
    if (tid < 32) { WeL[tid] = ldf(We, tid, isf); beL[tid] = ldf(be, tid, isf); bmL[tid] = bm0[tid]; }
    int s = tid >> 5, j = tid & 31;
    int n = blockIdx.x * 8 + s;
    __syncthreads();
    float xv = 0.f;
    if (n < N) {
        xv = lrelu(ldf(nf, n, isf) * WeL[j] + beL[j]);
        x[n * 32 + j] = xv;
        xs[s][j] = xv;
    }
    __syncthreads();
    if (n >= N) return;
    float acc = bmL[j];
#pragma unroll
    for (int k = 0; k < 32; ++k) acc += xs[s][k] * WL[k * 32 + j];
    m[n * 32 + j] = __float2bfloat16(lrelu(acc));
}

// ---------------- graph offsets from sorted batch ----------------
__global__ void k_graph_off(const int* __restrict__ batch, int* __restrict__ goff, int N) {
    int n = blockIdx.x * 256 + threadIdx.x;
    if (n >= N) return;
    int bn = batch[n];
    if (n == 0) {
        for (int g = 0; g <= bn; ++g) goff[g] = 0;
    } else {
        int bp = batch[n - 1];
        for (int g = bp + 1; g <= bn; ++g) goff[g] = n;
    }
    if (n == N - 1) {
        for (int g = bn + 1; g <= GG; ++g) goff[g] = N;
    }
}

// ---------------- fallback CSR build (B > 2048 only) ----------------
__global__ void k_hist(const int* __restrict__ dst, unsigned* __restrict__ deg, int E) {
    int e = blockIdx.x * 256 + threadIdx.x;
    if (e >= E) return;
    atomicAdd(&deg[dst[e]], 1u);
}
__global__ void k_scan1(const unsigned* __restrict__ deg, unsigned* __restrict__ excl,
                        unsigned* __restrict__ bsum, int N) {
    __shared__ unsigned s[256];
    int i = blockIdx.x * 256 + threadIdx.x;
    unsigned v = (i < N) ? deg[i] : 0u;
    s[threadIdx.x] = v;
    __syncthreads();
    for (int off = 1; off < 256; off <<= 1) {
        unsigned t = (threadIdx.x >= (unsigned)off) ? s[threadIdx.x - off] : 0u;
        __syncthreads();
        s[threadIdx.x] += t;
        __syncthreads();
    }
    if (i < N) excl[i] = s[threadIdx.x] - v;
    if (threadIdx.x == 255) bsum[blockIdx.x] = s[255];
}
__global__ void k_scan2(const unsigned* __restrict__ bsum, unsigned* __restrict__ boff, int nb) {
    __shared__ unsigned s[256];
    __shared__ unsigned carry;
    if (threadIdx.x == 0) carry = 0u;
    __syncthreads();
    for (int base = 0; base < nb; base += 256) {
        int i = base + threadIdx.x;
        unsigned v = (i < nb) ? bsum[i] : 0u;
        s[threadIdx.x] = v;
        __syncthreads();
        for (int off = 1; off < 256; off <<= 1) {
            unsigned t = (threadIdx.x >= (unsigned)off) ? s[threadIdx.x - off] : 0u;
            __syncthreads();
            s[threadIdx.x] += t;
            __syncthreads();
        }
        if (i < nb) boff[i] = carry + s[threadIdx.x] - v;
        __syncthreads();
        if (threadIdx.x == 0) carry += s[255];
        __syncthreads();
    }
}
__global__ void k_scan3(unsigned* __restrict__ indptr, const unsigned* __restrict__ boff,
                        unsigned* __restrict__ cursor, int N, int E) {
    int i = blockIdx.x * 256 + threadIdx.x;
    if (i >= N) return;
    unsigned v = indptr[i] + boff[i >> 8];
    indptr[i] = v;
    cursor[i] = v;
    if (i == 0) indptr[N] = (unsigned)E;
}
__global__ void k_scatter(const int* __restrict__ src, const int* __restrict__ dst,
                          unsigned* __restrict__ cursor, unsigned* __restrict__ ssrc, int E) {
    int e = blockIdx.x * 256 + threadIdx.x;
    if (e >= E) return;
    unsigned pos = atomicAdd(&cursor[dst[e]], 1u);
    ssrc[pos] = (unsigned)src[e];
}

// ---------------- bucketed CSR build ----------------
__global__ void k_bhist(const int* __restrict__ dst, unsigned* __restrict__ bcnt, int E, int B) {
    __shared__ unsigned h[2048];
    for (int t = threadIdx.x; t < B; t += 256) h[t] = 0;
    __syncthreads();
    int start = blockIdx.x * CHUNK, end = min(E, start + CHUNK);
    for (int e = start + threadIdx.x; e < end; e += 256)
        atomicAdd(&h[dst[e] >> 8], 1u);
    __syncthreads();
    for (int t = threadIdx.x; t < B; t += 256)
        if (h[t]) atomicAdd(&bcnt[t], h[t]);
}

__global__ void k_bscan(const unsigned* __restrict__ bcnt, unsigned* __restrict__ bbase,
                        unsigned* __restrict__ bcur, int B, int E) {
    __shared__ unsigned s[256];
    __shared__ unsigned carry;
    if (threadIdx.x == 0) carry = 0u;
    __syncthreads();
    for (int base = 0; base < B; base += 256) {
        int i = base + threadIdx.x;
        unsigned v = (i < B) ? bcnt[i] : 0u;
        s[threadIdx.x] = v;
        __syncthreads();
        for (int off = 1; off < 256; off <<= 1) {
            unsigned t = (threadIdx.x >= (unsigned)off) ? s[threadIdx.x - off] : 0u;
            __syncthreads();
            s[threadIdx.x] += t;
            __syncthreads();
        }
        if (i < B) {
            unsigned ex = carry + s[threadIdx.x] - v;
            bbase[i] = ex;
            bcur[i] = ex;
        }
        __syncthreads();
        if (threadIdx.x == 0) carry += s[255];
        __syncthreads();
    }
    if (threadIdx.x == 0) bbase[B] = (unsigned)E;
}

__global__ void k_binA(const int* __restrict__ src, const int* __restrict__ dst,
                       unsigned* __restrict__ bcur, unsigned long long* __restrict__ packed,
                       int E, int B) {
    __shared__ unsigned h[2048];
    __shared__ unsigned pos[2048];
    for (int t = threadIdx.x; t < B; t += 256) h[t] = 0;
    __syncthreads();
    int start = blockIdx.x * CHUNK, end = min(E, start + CHUNK);
    for (int e = start + threadIdx.x; e < end; e += 256)
        atomicAdd(&h[dst[e] >> 8], 1u);
    __syncthreads();
    for (int t = threadIdx.x; t < B; t += 256)
        pos[t] = h[t] ? atomicAdd(&bcur[t], h[t]) : 0u;
    __syncthreads();
    for (int e = start + threadIdx.x; e < end; e += 256) {
        int d = dst[e];
        unsigned p = atomicAdd(&pos[d >> 8], 1u);
        packed[p] = ((unsigned long long)(unsigned)d << 32) | (unsigned)src[e];
    }
}

// per-bucket: LDS degree count + scan -> indptr, then bucket-local scatter
__global__ void k_csr(const unsigned long long* __restrict__ packed,
                      const unsigned* __restrict__ bbase,
                      unsigned* __restrict__ indptr,
                      unsigned* __restrict__ ssrc, int N, int E) {
    __shared__ unsigned deg[256];
    __shared__ unsigned scn[256];
    __shared__ unsigned cur[256];
    int g = blockIdx.x, tid = threadIdx.x;
    int n0 = g << 8;
    int cnt = min(256, N - n0);
    deg[tid] = 0;
    __syncthreads();
    unsigned e0 = bbase[g], e1 = bbase[g + 1];
    for (unsigned e = e0 + tid; e < e1; e += 256) {
        int d = (int)(packed[e] >> 32);
        atomicAdd(&deg[d - n0], 1u);
    }
    __syncthreads();
    unsigned v = deg[tid];
    scn[tid] = v;
    __syncthreads();
    for (int off = 1; off < 256; off <<= 1) {
        unsigned t = (tid >= off) ? scn[tid - off] : 0u;
        __syncthreads();
        scn[tid] += t;
        __syncthreads();
    }
    unsigned start = e0 + scn[tid] - v;
    if (tid < cnt) { indptr[n0 + tid] = start; cur[tid] = start; }
    if (g == (int)gridDim.x - 1 && tid == 0) indptr[N] = (unsigned)E;
    __syncthreads();
    for (unsigned e = e0 + tid; e < e1; e += 256) {
        unsigned long long pk = packed[e];
        int d = (int)(pk >> 32);
        unsigned p = atomicAdd(&cur[d - n0], 1u);
        ssrc[p] = (unsigned)pk;
    }
}

// ---------------- fused step (round-6: 2-deep cross-node software pipeline) ----------------
// r5 inner code kept; loop restructured so the indptr->ssrc->m dependent chain of
// node k overlaps the compute phase of node k-1:
//   iter k: [fmax+agg of node k-1 (consumes m regs)] -> [issue m(k) from ss regs]
//           -> [issue meta(k+2)] -> [issue ssrc(k+1) from meta(k+1)]
//           -> [matmul/gate/feat/m_out of node k-1 (covers all issued latency)]
// Wf moved back to LDS (frees 32 VGPR for pipeline state). deg>32 tail (rare)
// handled serially in the fmax phase; empty/invalid nodes via clamped loads.
__global__ __launch_bounds__(256, 4)
void k_step(float* __restrict__ x, const __hip_bfloat16* __restrict__ m_in,
            __hip_bfloat16* __restrict__ m_out,
            const int* __restrict__ batch,
            const unsigned* __restrict__ indptr, const unsigned* __restrict__ ssrc,
            const float* __restrict__ Wa, const float* __restrict__ xgw,
            const float* __restrict__ Wg, const float* __restrict__ bg,
            const float* __restrict__ Wa1, const float* __restrict__ ba1,
            const float* __restrict__ Wf, const float* __restrict__ bf,
            const float* __restrict__ Wm_nx, const float* __restrict__ bm_nx,
            float* __restrict__ la1, float* __restrict__ U, float* __restrict__ S,
            int N, int hasNext) {
    __shared__ float WL[2048];    // Wa rows 0..31 then 64..95 (row-major, k*32+j)
    __shared__ float WmL[1024];
    __shared__ float WfL[1024];
    __shared__ float zL[8][64];   // [x(32) | agg(32)] per group
    __shared__ float xnL[8][32];
    __shared__ float WgL[32], W1L[32], bmL[32], bfL[32];
    __shared__ float bgL, b1L;
    int tid = threadIdx.x;
    for (int t = tid; t < 2048; t += 256) WL[t] = (t < 1024) ? Wa[t] : Wa[t + 1024];
    for (int t = tid; t < 1024; t += 256) WfL[t] = Wf[t];
    if (hasNext) {
        for (int t = tid; t < 1024; t += 256) WmL[t] = Wm_nx[t];
        if (tid < 32) bmL[tid] = bm_nx[tid];
    }
    if (tid < 32) { WgL[tid] = Wg[tid]; W1L[tid] = Wa1[tid]; bfL[tid] = bf[tid]; }
    if (tid == 0) { bgL = bg[0]; b1L = ba1[0]; }
    int s = tid >> 5, j = tid & 31;
    int c = j & 7, eo = j >> 3;
    const uint2* m2 = (const uint2*)m_in;
    int nbase = blockIdx.x * NPB;
    int rep = blockIdx.x & (NREP - 1);
    float* Urep = U + (size_t)rep * GG * 32;
    float* Srep = S + (size_t)rep * GG;
    __syncthreads();
    int gcur = -1;
    float Uacc = 0.f, Sacc = 0.f;

    // ---- pipeline register state ----
    // cm*: node in compute this iter; im*: node m-issued this iter;
    // pm*: node ssrc-issued this iter; qm*: meta loaded this iter.
    int   cmn = 0, cmv = 0, cmg = 0;  float cmx = 0.f;  unsigned cmst = 0, cmen = 0;
    int   imn, imv, img;              float imx;        unsigned imst, imen;
    int   pmn, pmv, pmg;              float pmx;        unsigned pmst, pmen;
    int   qn, qv, qg;                 float qx;         unsigned qst, qen;
    unsigned ssA, ssB, ssC, ssD, ssE, ssF, ssG, ssH;   // ssrc of im node (consumed at m-issue)
    unsigned srA, srB, srC, srD, srE, srF, srG, srH;   // ssrc of pm node (in flight)
    uint2 mA, mB, mC, mD, mE, mF, mG, mH;              // m in flight (im), consumed next iter

    auto metaLoad = [&](int sub, int& n_, int& v_, int& g_, float& x_, unsigned& st_, unsigned& en_) {
        int n = nbase + sub * 8 + s;
        int cl = (n < N) ? n : (N - 1);
        v_ = (sub < NPB / 8 && n < N) ? 1 : 0;
        n_ = cl;
        x_ = x[cl * 32 + j];
        g_ = batch[cl];
        st_ = indptr[cl];
        en_ = indptr[cl + 1];
    };
    auto ssrcIssue = [&](unsigned st_, unsigned en_,
                         unsigned& a0, unsigned& a1, unsigned& a2, unsigned& a3,
                         unsigned& a4, unsigned& a5, unsigned& a6, unsigned& a7) {
        unsigned b = (en_ > st_) ? st_ : 0u;
        unsigned last = (en_ > st_) ? (en_ - 1) : 0u;
        a0 = ssrc[min(b + eo, last)];
        a1 = ssrc[min(b + 4 + eo, last)];
        a2 = ssrc[min(b + 8 + eo, last)];
        a3 = ssrc[min(b + 12 + eo, last)];
        a4 = ssrc[min(b + 16 + eo, last)];
        a5 = ssrc[min(b + 20 + eo, last)];
        a6 = ssrc[min(b + 24 + eo, last)];
        a7 = ssrc[min(b + 28 + eo, last)];
    };

    // ---- prologue: meta(0), meta(1), ssrc(0) ----
    metaLoad(0, imn, imv, img, imx, imst, imen);
    metaLoad(1, pmn, pmv, pmg, pmx, pmst, pmen);
    ssrcIssue(imst, imen, ssA, ssB, ssC, ssD, ssE, ssF, ssG, ssH);

    for (int sub = 0; sub <= NPB / 8; ++sub) {
        float a0 = -INFINITY, a1 = -INFINITY, a2 = -INFINITY, a3 = -INFINITY;
        // ---- compute part 1: fmax reduce of node sub-1 (consumes m regs) ----
        if (sub >= 1) {
            a0 = fmaxf(fmaxf(fmaxf(bfLo(mA.x), bfLo(mB.x)), fmaxf(bfLo(mC.x), bfLo(mD.x))),
                       fmaxf(fmaxf(bfLo(mE.x), bfLo(mF.x)), fmaxf(bfLo(mG.x), bfLo(mH.x))));
            a1 = fmaxf(fmaxf(fmaxf(bfHi(mA.x), bfHi(mB.x)), fmaxf(bfHi(mC.x), bfHi(mD.x))),
                       fmaxf(fmaxf(bfHi(mE.x), bfHi(mF.x)), fmaxf(bfHi(mG.x), bfHi(mH.x))));
            a2 = fmaxf(fmaxf(fmaxf(bfLo(mA.y), bfLo(mB.y)), fmaxf(bfLo(mC.y), bfLo(mD.y))),
                       fmaxf(fmaxf(bfLo(mE.y), bfLo(mF.y)), fmaxf(bfLo(mG.y), bfLo(mH.y))));
            a3 = fmaxf(fmaxf(fmaxf(bfHi(mA.y), bfHi(mB.y)), fmaxf(bfHi(mC.y), bfHi(mD.y))),
                       fmaxf(fmaxf(bfHi(mE.y), bfHi(mF.y)), fmaxf(bfHi(mG.y), bfHi(mH.y))));
            // rare deg>32 tail: serial gather (uniform branch per group)
            if (cmen > cmst + 32) {
                unsigned last = cmen - 1;
                for (unsigned base = cmst + 32; base < cmen; base += 32) {
                    unsigned tA = ssrc[min(base + eo, last)];
                    unsigned tB = ssrc[min(base + 4 + eo, last)];
                    unsigned tC = ssrc[min(base + 8 + eo, last)];
                    unsigned tD = ssrc[min(base + 12 + eo, last)];
                    unsigned tE = ssrc[min(base + 16 + eo, last)];
                    unsigned tF = ssrc[min(base + 20 + eo, last)];
                    unsigned tG = ssrc[min(base + 24 + eo, last)];
                    unsigned tH = ssrc[min(base + 28 + eo, last)];
                    uint2 wA = m2[tA * 8 + c];
                    uint2 wB = m2[tB * 8 + c];
                    uint2 wC = m2[tC * 8 + c];
                    uint2 wD = m2[tD * 8 + c];
                    uint2 wE = m2[tE * 8 + c];
                    uint2 wF = m2[tF * 8 + c];
                    uint2 wG = m2[tG * 8 + c];
                    uint2 wH = m2[tH * 8 + c];
                    a0 = fmaxf(a0, fmaxf(fmaxf(fmaxf(bfLo(wA.x), bfLo(wB.x)), fmaxf(bfLo(wC.x), bfLo(wD.x))),
                                         fmaxf(fmaxf(bfLo(wE.x), bfLo(wF.x)), fmaxf(bfLo(wG.x), bfLo(wH.x)))));
                    a1 = fmaxf(a1, fmaxf(fmaxf(fmaxf(bfHi(wA.x), bfHi(wB.x)), fmaxf(bfHi(wC.x), bfHi(wD.x))),
                                         fmaxf(fmaxf(bfHi(wE.x), bfHi(wF.x)), fmaxf(bfHi(wG.x), bfHi(wH.x)))));
                    a2 = fmaxf(a2, fmaxf(fmaxf(fmaxf(bfLo(wA.y), bfLo(wB.y)), fmaxf(bfLo(wC.y), bfLo(wD.y))),
                                         fmaxf(fmaxf(bfLo(wE.y), bfLo(wF.y)), fmaxf(bfLo(wG.y), bfLo(wH.y)))));
                    a3 = fmaxf(a3, fmaxf(fmaxf(fmaxf(bfHi(wA.y), bfHi(wB.y)), fmaxf(bfHi(wC.y), bfHi(wD.y))),
                                         fmaxf(fmaxf(bfHi(wE.y), bfHi(wF.y)), fmaxf(bfHi(wG.y), bfHi(wH.y)))));
                }
            }
        }
        // ---- issue phase: m(sub), meta(sub+2), ssrc(sub+1) ----
        if (sub < NPB / 8) {
            mA = m2[ssA * 8 + c];
            mB = m2[ssB * 8 + c];
            mC = m2[ssC * 8 + c];
            mD = m2[ssD * 8 + c];
            mE = m2[ssE * 8 + c];
            mF = m2[ssF * 8 + c];
            mG = m2[ssG * 8 + c];
            mH = m2[ssH * 8 + c];
            metaLoad(sub + 2, qn, qv, qg, qx, qst, qen);
            ssrcIssue(pmst, pmen, srA, srB, srC, srD, srE, srF, srG, srH);
        }
        // ---- compute part 2: reduce + MLPs of node sub-1 (covers issued latency) ----
        if (sub >= 1 && cmv) {
            a0 = fmaxf(a0, __shfl_xor(a0, 8));
            a0 = fmaxf(a0, __shfl_xor(a0, 16));
            a1 = fmaxf(a1, __shfl_xor(a1, 8));
            a1 = fmaxf(a1, __shfl_xor(a1, 16));
            a2 = fmaxf(a2, __shfl_xor(a2, 8));
            a2 = fmaxf(a2, __shfl_xor(a2, 16));
            a3 = fmaxf(a3, __shfl_xor(a3, 8));
            a3 = fmaxf(a3, __shfl_xor(a3, 16));
            if (cmg != gcur) {
                if (gcur >= 0) {
                    atomicAdd(&Urep[gcur * 32 + j], Uacc);
                    if (j == 0) atomicAdd(&Srep[gcur], Sacc);
                }
                gcur = cmg; Uacc = 0.f; Sacc = 0.f;
            }
            zL[s][j] = cmx;
            if (eo == 0) {
                bool empty = (cmst == cmen);
                zL[s][32 + (c << 2) + 0] = empty ? 0.f : a0;
                zL[s][32 + (c << 2) + 1] = empty ? 0.f : a1;
                zL[s][32 + (c << 2) + 2] = empty ? 0.f : a2;
                zL[s][32 + (c << 2) + 3] = empty ? 0.f : a3;
            }
            float acc0 = xgw[cmg * 32 + j];
            float acc1 = 0.f;
#pragma unroll
            for (int k = 0; k < 64; k += 2) {
                acc0 += zL[s][k] * WL[k * 32 + j];
                acc1 += zL[s][k + 1] * WL[(k + 1) * 32 + j];
            }
            float xn = lrelu(acc0 + acc1) + cmx;
            x[cmn * 32 + j] = xn;
            xnL[s][j] = xn;
            float lv = xn * WgL[j];
            if (hasNext) {
#pragma unroll
                for (int off = 16; off; off >>= 1) lv += __shfl_xor(lv, off);
            } else {
                float l1 = xn * W1L[j];
#pragma unroll
                for (int off = 16; off; off >>= 1) { lv += __shfl_xor(lv, off); l1 += __shfl_xor(l1, off); }
                if (j == 0) la1[cmn] = l1 + b1L;
            }
            float e = __expf(lv + bgL);
            float f = bfL[j];
            if (hasNext) {
                float a20 = bmL[j], a21 = 0.f;
#pragma unroll
                for (int k = 0; k < 32; k += 2) {
                    float v0 = xnL[s][k], v1 = xnL[s][k + 1];
                    f += v0 * WfL[k * 32 + j] + v1 * WfL[(k + 1) * 32 + j];
                    a20 += v0 * WmL[k * 32 + j];
                    a21 += v1 * WmL[(k + 1) * 32 + j];
                }
                m_out[cmn * 32 + j] = __float2bfloat16(lrelu(a20 + a21));
            } else {
#pragma unroll
                for (int k = 0; k < 32; ++k) f += xnL[s][k] * WfL[k * 32 + j];
            }
            Uacc += e * lrelu(f);
            Sacc += e;
        }
        // ---- rotate pipeline state ----
        cmn = imn; cmv = imv; cmg = img; cmx = imx; cmst = imst; cmen = imen;
        imn = pmn; imv = pmv; img = pmg; imx = pmx; imst = pmst; imen = pmen;
        pmn = qn;  pmv = qv;  pmg = qg;  pmx = qx;  pmst = qst;  pmen = qen;
        ssA = srA; ssB = srB; ssC = srC; ssD = srD;
        ssE = srE; ssF = srF; ssG = srG; ssH = srH;
    }
    if (gcur >= 0) {
        atomicAdd(&Urep[gcur * 32 + j], Uacc);
        if (j == 0) atomicAdd(&Srep[gcur], Sacc);
    }
}

// ---------------- reduce replicas + xg transform + residual + reset + next xgw ------------
// One block per graph (128 blocks), 8-way replica split + LDS reduce.
__global__ void k_gupd(float* __restrict__ U, float* __restrict__ S,
                       const float* __restrict__ xg_in,
                       const float* __restrict__ Wt, const float* __restrict__ bt,
                       float* __restrict__ xg_out,
                       const float* __restrict__ WaNx, const float* __restrict__ baNx,
                       float* __restrict__ xgw, int hasNext) {
    __shared__ float Up[8][32];
    __shared__ float Sp[8];
    __shared__ float pl[32];
    __shared__ float vL[32];
    int g = blockIdx.x;
    int tid = threadIdx.x;
    int rp = tid >> 5, j = tid & 31;
    float usum = 0.f, ssum = 0.f;
    for (int r = rp; r < NREP; r += 8) {
        size_t ui = (size_t)r * GG * 32 + g * 32 + j;
        usum += U[ui];
        U[ui] = 0.f;   // reset for next step
        if (j == 0) { ssum += S[r * GG + g]; S[r * GG + g] = 0.f; }
    }
    Up[rp][j] = usum;
    if (j == 0) Sp[rp] = ssum;
    __syncthreads();
    if (rp == 0) {
        float ut = 0.f;
#pragma unroll
        for (int i = 0; i < 8; ++i) ut += Up[i][j];
        float st = ((Sp[0] + Sp[1]) + (Sp[2] + Sp[3])) + ((Sp[4] + Sp[5]) + (Sp[6] + Sp[7]));
        float inv = (st > 0.f) ? 1.f / st : 0.f;
        pl[j] = ut * inv;             // wave-synchronous within the 32-lane group
        float xgv = xg_in[g * 32 + j];
        vL[j] = xgv;
        float acc = bt[j];
#pragma unroll
        for (int k = 0; k < 32; ++k) acc += pl[k] * Wt[k * 32 + j];
#pragma unroll
        for (int k = 0; k < 32; ++k) acc += vL[k] * Wt[(32 + k) * 32 + j];
        float v = lrelu(acc) + xgv;
        xg_out[g * 32 + j] = v;
        if (hasNext) {
            vL[j] = v;                // same wave -> ordered
            float aw = baNx[j];
#pragma unroll
            for (int k = 0; k < 32; ++k) aw += vL[k] * WaNx[(32 + k) * 32 + j];
            xgw[g * 32 + j] = aw;
        }
    }
}

// ---------------- final: a1 softmax + value + a0 probs ----------------
__global__ void k_final(const float* __restrict__ logits, const int* __restrict__ goff,
                        const float* __restrict__ xg,
                        const void* __restrict__ Wv, const void* __restrict__ bv,
                        const void* __restrict__ Wa0, const void* __restrict__ ba0,
                        void* __restrict__ out, int N, const int* __restrict__ dtf) {
    __shared__ float red[256];
    int isf = *dtf;
    int g = blockIdx.x, tid = threadIdx.x;
    int s0 = goff[g], s1 = goff[g + 1];
    float lm = -INFINITY;
    for (int n = s0 + tid; n < s1; n += 256) lm = fmaxf(lm, logits[n]);
    red[tid] = lm;
    __syncthreads();
    for (int off = 128; off; off >>= 1) {
        if (tid < off) red[tid] = fmaxf(red[tid], red[tid + off]);
        __syncthreads();
    }
    float gmax = red[0];
    __syncthreads();
    float ls = 0.f;
    for (int n = s0 + tid; n < s1; n += 256) ls += expf(logits[n] - gmax);
    red[tid] = ls;
    __syncthreads();
    for (int off = 128; off; off >>= 1) {
        if (tid < off) red[tid] += red[tid + off];
        __syncthreads();
    }
    float inv = (red[0] > 0.f) ? 1.f / red[0] : 0.f;
    __syncthreads();
    for (int n = s0 + tid; n < s1; n += 256)
        stf(out, 384 + n, expf(logits[n] - gmax) * inv, isf);
    if (tid == 0) {
        float acc = ldf(bv, 0, isf);
        for (int k = 0; k < 32; ++k) acc += xg[g * 32 + k] * ldf(Wv, k, isf);
        stf(out, g, acc, isf);
        float l0 = ldf(ba0, 0, isf), l1 = ldf(ba0, 1, isf);
        for (int k = 0; k < 32; ++k) {
            float xv = xg[g * 32 + k];
            l0 += xv * ldf(Wa0, k * 2, isf);
            l1 += xv * ldf(Wa0, k * 2 + 1, isf);
        }
        float mm = fmaxf(l0, l1);
        float e0 = expf(l0 - mm), e1 = expf(l1 - mm);
        float si = 1.f / (e0 + e1);
        stf(out, 128 + 2 * g, e0 * si, isf);
        stf(out, 128 + 2 * g + 1, e1 * si, isf);
    }
}

extern "C" void kernel_launch(void* const* d_in, const int* in_sizes, int n_in,
                              void* d_out, int out_size, void* d_ws, size_t ws_size,
                              hipStream_t stream) {
    const void* nf      = d_in[0];
    const int*  eidx    = (const int*)d_in[1];
    const int*  batch   = (const int*)d_in[2];
    const void* W_embed = d_in[4];
    const void* b_embed = d_in[5];
    const void* Wm      = d_in[6];
    const void* bm      = d_in[7];
    const void* Wa      = d_in[8];
    const void* ba      = d_in[9];
    const void* Wgate   = d_in[10];
    const void* bgate   = d_in[11];
    const void* Wfeat   = d_in[12];
    const void* bfeat   = d_in[13];
    const void* Wt      = d_in[14];
    const void* bt      = d_in[15];
    const void* W_v     = d_in[16];
    const void* b_v     = d_in[17];
    const void* W_a0    = d_in[18];
    const void* b_a0    = d_in[19];
    const void* W_a1    = d_in[20];
    const void* b_a1    = d_in[21];

    const int N = in_sizes[0];
    const int E = in_sizes[1] / 2;
    const int nWm = in_sizes[6];  // 3*32*32 = 3072
    const int* src = eidx;
    const int* dst = eidx + E;
    const int B = (N + 255) >> 8;

    char* ws = (char*)d_ws;
    size_t off = 0;
    auto alloc = [&](size_t bytes) -> char* {
        char* p = ws + off;
        off = (off + bytes + 255) & ~(size_t)255;
        return p;
    };
    float*          x      = (float*)alloc((size_t)N * 32 * 4);
    // packed (E*8 B) aliases m_a+m_b (2 * N*32*2 B): packed dead after k_csr.
    size_t mBytes  = (size_t)N * 32 * 2;
    size_t pkBytes = (size_t)E * 8;
    size_t rBytes  = (2 * mBytes > pkBytes) ? 2 * mBytes : pkBytes;
    char*  mRegion = alloc(rBytes);
    unsigned long long* packed = (unsigned long long*)mRegion;
    __hip_bfloat16*     m_a    = (__hip_bfloat16*)mRegion;
    __hip_bfloat16*     m_b    = (__hip_bfloat16*)(mRegion + mBytes);
    float*          la1    = (float*)alloc((size_t)N * 4);
    unsigned*       indptr = (unsigned*)alloc((size_t)(N + 1) * 4);
    unsigned*       cursor = (unsigned*)alloc((size_t)N * 4);
    unsigned*       ssrc   = (unsigned*)alloc((size_t)(E + 16) * 4);
    const int nb = (N + 255) / 256;
    unsigned*       bsum   = (unsigned*)alloc((size_t)nb * 4);
    unsigned*       boff   = (unsigned*)alloc((size_t)nb * 4);
    unsigned*       bcnt   = (unsigned*)alloc((size_t)(B + 1) * 4);
    unsigned*       bbase  = (unsigned*)alloc((size_t)(B + 1) * 4);
    unsigned*       bcur   = (unsigned*)alloc((size_t)(B + 1) * 4);
    int*            goff   = (int*)alloc((size_t)(GG + 1) * 4);
    float*          xg_a   = (float*)alloc((size_t)GG * 32 * 4);
    float*          xg_b   = (float*)alloc((size_t)GG * 32 * 4);
    float*          xgw    = (float*)alloc((size_t)GG * 32 * 4);
    float*          U      = (float*)alloc((size_t)NREP * GG * 32 * 4);
    float*          S      = (float*)alloc((size_t)NREP * GG * 4);
    int*            dtf    = (int*)alloc(256);
    float*          wcat   = (float*)alloc((size_t)WCAT_N * 4);

    const int nB_n  = (N + 255) / 256;
    const int nB_e  = (E + 255) / 256;
    const int nB_n8 = (N + 7) / 8;
    const int nB_st = (N + NPB - 1) / NPB;
    const int nB_ch = (E + CHUNK - 1) / CHUNK;

    hipMemsetAsync(xg_a, 0, (size_t)GG * 32 * 4, stream);
    hipMemsetAsync(bcnt, 0, (size_t)(B + 1) * 4, stream);
    hipMemsetAsync(U, 0, (size_t)NREP * GG * 32 * 4, stream);
    hipMemsetAsync(S, 0, (size_t)NREP * GG * 4, stream);

    k_detect<<<1, 256, 0, stream>>>((const unsigned short*)Wm, nWm, dtf);

    CvtArgs ca;
    const void* ps[12] = {Wm, bm, Wa, ba, Wgate, bgate, Wfeat, bfeat, Wt, bt, W_a1, b_a1};
    const int  offs[12] = {OFF_Wm, OFF_bm, OFF_Wa, OFF_ba, OFF_Wg, OFF_bg,
                           OFF_Wf, OFF_bf, OFF_Wt, OFF_bt, OFF_Wa1, OFF_ba1};
    const int  ns[12]  = {3072, 96, 9216, 96, 96, 3, 3072, 96, 6144, 96, 32, 1};
    for (int i = 0; i < 12; ++i) { ca.p[i] = ps[i]; ca.off[i] = offs[i]; ca.n[i] = ns[i]; }
    k_cvt_all<<<dim3(36, 12), 256, 0, stream>>>(ca, wcat, dtf);

    // step-0 xgw: xg = 0 -> xgw = ba[0] broadcast
    k_xgw0<<<(GG * 32) / 256, 256, 0, stream>>>(ba, xgw, dtf);

    k_graph_off<<<nB_n, 256, 0, stream>>>(batch, goff, N);

    // CSR build first (packed aliases m buffers; m written after)
    if (B <= 2048) {
        k_bhist<<<nB_ch, 256, 0, stream>>>(dst, bcnt, E, B);
        k_bscan<<<1, 256, 0, stream>>>(bcnt, bbase, bcur, B, E);
        k_binA<<<nB_ch, 256, 0, stream>>>(src, dst, bcur, packed, E, B);
        k_csr<<<B, 256, 0, stream>>>(packed, bbase, indptr, ssrc, N, E);
    } else {
        hipMemsetAsync(cursor, 0, (size_t)N * 4, stream);
        k_hist<<<nB_e, 256, 0, stream>>>(dst, cursor, E);
        k_scan1<<<nb, 256, 0, stream>>>(cursor, indptr, bsum, N);
        k_scan2<<<1, 256, 0, stream>>>(bsum, boff, nb);
        k_scan3<<<nB_n, 256, 0, stream>>>(indptr, boff, cursor, N, E);
        k_scatter<<<nB_e, 256, 0, stream>>>(src, dst, cursor, ssrc, E);
    }

    // embed + step-0 message (node-major m)
    k_embed_msg<<<nB_n8, 256, 0, stream>>>(nf, W_embed, b_embed,
                                           wcat + OFF_Wm, wcat + OFF_bm, x, m_a, N, dtf);

    float* xg_cur = xg_a;
    float* xg_nxt = xg_b;
    __hip_bfloat16* m_cur = m_a;
    __hip_bfloat16* m_nxt = m_b;
    for (int i = 0; i < 3; ++i) {
        int hasNext = (i < 2) ? 1 : 0;
        k_step<<<nB_st, 256, 0, stream>>>(x, m_cur, m_nxt, batch, indptr, ssrc,
                                          wcat + OFF_Wa + i * 3072, xgw,
                                          wcat + OFF_Wg + i * 32, wcat + OFF_bg + i,
                                          wcat + OFF_Wa1, wcat + OFF_ba1,
                                          wcat + OFF_Wf + i * 1024, wcat + OFF_bf + i * 32,
                                          wcat + OFF_Wm + (i + 1) * 1024,
                                          wcat + OFF_bm + (i + 1) * 32,
                                          la1, U, S, N, hasNext);
        k_gupd<<<GG, 256, 0, stream>>>(U, S, xg_cur,
                                       wcat + OFF_Wt + i * 2048,
                                       wcat + OFF_bt + i * 32, xg_nxt,
                                       wcat + OFF_Wa + (i + 1) * 3072,
                                       wcat + OFF_ba + (i + 1) * 32,
                                       xgw, hasNext);
        float* tmp = xg_cur; xg_cur = xg_nxt; xg_nxt = tmp;
        __hip_bfloat16* tm = m_cur; m_cur = m_nxt; m_nxt = tm;
    }

    k_final<<<GG, 256, 0, stream>>>(la1, goff, xg_cur, W_v, b_v, W_a0, b_a0,
                                    d_out, N, dtf);
}

// Round 7
// 567.015 us; speedup vs baseline: 1.2378x; 1.2378x over previous
//
#include <hip/hip_runtime.h>
#include <hip/hip_bf16.h>

#define GG 128
#define SLOPE 0.01f
#define CHUNK 8192
#define NPB 64   // nodes per block in k_step
#define NREP 64  // accumulator replicas (atomic contention striping)

// wcat element offsets (f32 staged weights)
#define OFF_Wm   0
#define OFF_bm   3072
#define OFF_Wa   3168
#define OFF_ba   12384
#define OFF_Wg   12480
#define OFF_bg   12576
#define OFF_Wf   12592
#define OFF_bf   15664
#define OFF_Wt   15760
#define OFF_bt   21904
#define OFF_Wa1  22000
#define OFF_ba1  22032
#define WCAT_N   22048

__device__ __forceinline__ float lrelu(float v) { return v > 0.f ? v : SLOPE * v; }

__device__ __forceinline__ float ldf(const void* p, int i, int isf) {
    if (isf) return ((const float*)p)[i];
    return __bfloat162float(((const __hip_bfloat16*)p)[i]);
}
__device__ __forceinline__ void stf(void* p, int i, float v, int isf) {
    if (isf) ((float*)p)[i] = v;
    else ((__hip_bfloat16*)p)[i] = __float2bfloat16(v);
}

// bf16-pair unpack from u32 (bit ops only)
__device__ __forceinline__ float bfLo(unsigned u) { return __uint_as_float(u << 16); }
__device__ __forceinline__ float bfHi(unsigned u) { return __uint_as_float(u & 0xFFFF0000u); }

// ---------------- dtype detection + bcnt zero ----------------
__global__ void k_detect(const unsigned short* __restrict__ w, int n, int* __restrict__ flag,
                         unsigned* __restrict__ bcnt, int B) {
    __shared__ int bad;
    for (int t = threadIdx.x; t <= B; t += 256) bcnt[t] = 0u;
    if (threadIdx.x == 0) bad = 0;
    __syncthreads();
    for (int t = threadIdx.x; t < n; t += 256) {
        unsigned short u = w[t];
        int e = (u >> 7) & 0xFF;
        if (e >= 141) bad = 1;  // benign same-value race
    }
    __syncthreads();
    if (threadIdx.x == 0) { flag[0] = bad; flag[32] = 1; }
}

// ---------------- fused prep: cvt + xgw0 + graph_off + bhist + zero-fills ----------------
struct CvtArgs {
    const void* p[12];
    int off[12];
    int n[12];
};
// block ranges: [0,432) cvt | [432,448) xgw0 | [..,+cG) graph_off | [..,+cH) bhist | [..,+268) fills
__global__ void k_prep(CvtArgs a, float* __restrict__ wcat, const int* __restrict__ dtf,
                       const void* __restrict__ ba0, float* __restrict__ xgw,
                       const int* __restrict__ batch, int* __restrict__ goff, int N,
                       const int* __restrict__ dst, unsigned* __restrict__ bcnt, int E, int B,
                       float* __restrict__ xg_a, float* __restrict__ U, float* __restrict__ S) {
    __shared__ unsigned h[2048];
    int blk = blockIdx.x;
    int tid = threadIdx.x;
    const int cG = (N + 255) >> 8;
    const int cH = (E + CHUNK - 1) / CHUNK;
    if (blk < 432) {  // weight staging to f32
        int seg = blk / 36;
        int i = (blk % 36) * 256 + tid;
        int isf = *dtf;
        if (i < a.n[seg]) wcat[a.off[seg] + i] = ldf(a.p[seg], i, isf);
        return;
    }
    blk -= 432;
    if (blk < 16) {   // step-0 xgw = ba0 broadcast
        int isf = *dtf;
        int idx = blk * 256 + tid;
        xgw[idx] = ldf(ba0, idx & 31, isf);
        return;
    }
    blk -= 16;
    if (blk < cG) {   // graph offsets from sorted batch
        int n = blk * 256 + tid;
        if (n >= N) return;
        int bn = batch[n];
        if (n == 0) {
            for (int g = 0; g <= bn; ++g) goff[g] = 0;
        } else {
            int bp = batch[n - 1];
            for (int g = bp + 1; g <= bn; ++g) goff[g] = n;
        }
        if (n == N - 1) {
            for (int g = bn + 1; g <= GG; ++g) goff[g] = N;
        }
        return;
    }
    blk -= cG;
    if (blk < cH) {   // bucket histogram (bucketed path only)
        if (B > 2048) return;
        for (int t = tid; t < B; t += 256) h[t] = 0;
        __syncthreads();
        int start = blk * CHUNK, end = min(E, start + CHUNK);
        for (int e = start + tid; e < end; e += 256)
            atomicAdd(&h[dst[e] >> 8], 1u);
        __syncthreads();
        for (int t = tid; t < B; t += 256)
            if (h[t]) atomicAdd(&bcnt[t], h[t]);
        return;
    }
    blk -= cH;
    {   // zero fills: U (65536 f4) | S (2048 f4) | xg_a (1024 f4)
        float4 z4 = make_float4(0.f, 0.f, 0.f, 0.f);
        long long fi = (long long)blk * 256 + tid;
        if (fi < 65536) { ((float4*)U)[fi] = z4; return; }
        fi -= 65536;
        if (fi < 2048) { ((float4*)S)[fi] = z4; return; }
        fi -= 2048;
        if (fi < 1024) { ((float4*)xg_a)[fi] = z4; return; }
    }
}

// ---------------- fallback CSR build (B > 2048 only) ----------------
__global__ void k_hist(const int* __restrict__ dst, unsigned* __restrict__ deg, int E) {
    int e = blockIdx.x * 256 + threadIdx.x;
    if (e >= E) return;
    atomicAdd(&deg[dst[e]], 1u);
}
__global__ void k_scan1(const unsigned* __restrict__ deg, unsigned* __restrict__ excl,
                        unsigned* __restrict__ bsum, int N) {
    __shared__ unsigned s[256];
    int i = blockIdx.x * 256 + threadIdx.x;
    unsigned v = (i < N) ? deg[i] : 0u;
    s[threadIdx.x] = v;
    __syncthreads();
    for (int off = 1; off < 256; off <<= 1) {
        unsigned t = (threadIdx.x >= (unsigned)off) ? s[threadIdx.x - off] : 0u;
        __syncthreads();
        s[threadIdx.x] += t;
        __syncthreads();
    }
    if (i < N) excl[i] = s[threadIdx.x] - v;
    if (threadIdx.x == 255) bsum[blockIdx.x] = s[255];
}
__global__ void k_scan2(const unsigned* __restrict__ bsum, unsigned* __restrict__ boff, int nb) {
    __shared__ unsigned s[256];
    __shared__ unsigned carry;
    if (threadIdx.x == 0) carry = 0u;
    __syncthreads();
    for (int base = 0; base < nb; base += 256) {
        int i = base + threadIdx.x;
        unsigned v = (i < nb) ? bsum[i] : 0u;
        s[threadIdx.x] = v;
        __syncthreads();
        for (int off = 1; off < 256; off <<= 1) {
            unsigned t = (threadIdx.x >= (unsigned)off) ? s[threadIdx.x - off] : 0u;
            __syncthreads();
            s[threadIdx.x] += t;
            __syncthreads();
        }
        if (i < nb) boff[i] = carry + s[threadIdx.x] - v;
        __syncthreads();
        if (threadIdx.x == 0) carry += s[255];
        __syncthreads();
    }
}
__global__ void k_scan3(unsigned* __restrict__ indptr, const unsigned* __restrict__ boff,
                        unsigned* __restrict__ cursor, int N, int E) {
    int i = blockIdx.x * 256 + threadIdx.x;
    if (i >= N) return;
    unsigned v = indptr[i] + boff[i >> 8];
    indptr[i] = v;
    cursor[i] = v;
    if (i == 0) indptr[N] = (unsigned)E;
}
__global__ void k_scatter(const int* __restrict__ src, const int* __restrict__ dst,
                          unsigned* __restrict__ cursor, unsigned* __restrict__ ssrc, int E) {
    int e = blockIdx.x * 256 + threadIdx.x;
    if (e >= E) return;
    unsigned pos = atomicAdd(&cursor[dst[e]], 1u);
    ssrc[pos] = (unsigned)src[e];
}

// ---------------- bucketed scan ----------------
__global__ void k_bscan(const unsigned* __restrict__ bcnt, unsigned* __restrict__ bbase,
                        unsigned* __restrict__ bcur, int B, int E) {
    __shared__ unsigned s[256];
    __shared__ unsigned carry;
    if (threadIdx.x == 0) carry = 0u;
    __syncthreads();
    for (int base = 0; base < B; base += 256) {
        int i = base + threadIdx.x;
        unsigned v = (i < B) ? bcnt[i] : 0u;
        s[threadIdx.x] = v;
        __syncthreads();
        for (int off = 1; off < 256; off <<= 1) {
            unsigned t = (threadIdx.x >= (unsigned)off) ? s[threadIdx.x - off] : 0u;
            __syncthreads();
            s[threadIdx.x] += t;
            __syncthreads();
        }
        if (i < B) {
            unsigned ex = carry + s[threadIdx.x] - v;
            bbase[i] = ex;
            bcur[i] = ex;
        }
        __syncthreads();
        if (threadIdx.x == 0) carry += s[255];
        __syncthreads();
    }
    if (threadIdx.x == 0) bbase[B] = (unsigned)E;
}

// ---------------- fused work: binA (bucket binning) || embed+step-0 message ----------------
// binA blocks [0,nbA); embed blocks [nbA, nbA+nbE). Independent work, one launch.
// NOTE: packed no longer aliases m buffers (separate ws region) so this overlap is safe.
__global__ void k_work(const int* __restrict__ src, const int* __restrict__ dst,
                       unsigned* __restrict__ bcur, unsigned long long* __restrict__ packed,
                       int E, int B, int nbA,
                       const void* __restrict__ nf, const void* __restrict__ We,
                       const void* __restrict__ be,
                       const float* __restrict__ Wm0, const float* __restrict__ bm0,
                       float* __restrict__ x, __hip_bfloat16* __restrict__ m, int N,
                       const int* __restrict__ dtf) {
    __shared__ unsigned h[2048];
    __shared__ unsigned pos[2048];
    __shared__ float WL[1024];
    __shared__ float WeL[32], beL[32], bmL[32];
    __shared__ float xs[8][32];
    int tid = threadIdx.x;
    if ((int)blockIdx.x < nbA) {
        // ---- binA ----
        for (int t = tid; t < B; t += 256) h[t] = 0;
        __syncthreads();
        int start = blockIdx.x * CHUNK, end = min(E, start + CHUNK);
        for (int e = start + tid; e < end; e += 256)
            atomicAdd(&h[dst[e] >> 8], 1u);
        __syncthreads();
        for (int t = tid; t < B; t += 256)
            pos[t] = h[t] ? atomicAdd(&bcur[t], h[t]) : 0u;
        __syncthreads();
        for (int e = start + tid; e < end; e += 256) {
            int d = dst[e];
            unsigned p = atomicAdd(&pos[d >> 8], 1u);
            packed[p] = ((unsigned long long)(unsigned)d << 32) | (unsigned)src[e];
        }
        return;
    }
    // ---- embed + step-0 message ----
    int blkE = blockIdx.x - nbA;
    int isf = *dtf;
    for (int t = tid; t < 1024; t += 256) WL[t] = Wm0[t];
    if (tid < 32) { WeL[tid] = ldf(We, tid, isf); beL[tid] = ldf(be, tid, isf); bmL[tid] = bm0[tid]; }
    int s = tid >> 5, j = tid & 31;
    int n = blkE * 8 + s;
    __syncthreads();
    float xv = 0.f;
    if (n < N) {
        xv = lrelu(ldf(nf, n, isf) * WeL[j] + beL[j]);
        x[n * 32 + j] = xv;
        xs[s][j] = xv;
    }
    __syncthreads();
    if (n >= N) return;
    float acc = bmL[j];
#pragma unroll
    for (int k = 0; k < 32; ++k) acc += xs[s][k] * WL[k * 32 + j];
    m[n * 32 + j] = __float2bfloat16(lrelu(acc));
}

// per-bucket: LDS degree count + scan -> indptr, then bucket-local scatter
__global__ void k_csr(const unsigned long long* __restrict__ packed,
                      const unsigned* __restrict__ bbase,
                      unsigned* __restrict__ indptr,
                      unsigned* __restrict__ ssrc, int N, int E) {
    __shared__ unsigned deg[256];
    __shared__ unsigned scn[256];
    __shared__ unsigned cur[256];
    int g = blockIdx.x, tid = threadIdx.x;
    int n0 = g << 8;
    int cnt = min(256, N - n0);
    deg[tid] = 0;
    __syncthreads();
    unsigned e0 = bbase[g], e1 = bbase[g + 1];
    for (unsigned e = e0 + tid; e < e1; e += 256) {
        int d = (int)(packed[e] >> 32);
        atomicAdd(&deg[d - n0], 1u);
    }
    __syncthreads();
    unsigned v = deg[tid];
    scn[tid] = v;
    __syncthreads();
    for (int off = 1; off < 256; off <<= 1) {
        unsigned t = (tid >= off) ? scn[tid - off] : 0u;
        __syncthreads();
        scn[tid] += t;
        __syncthreads();
    }
    unsigned start = e0 + scn[tid] - v;
    if (tid < cnt) { indptr[n0 + tid] = start; cur[tid] = start; }
    if (g == (int)gridDim.x - 1 && tid == 0) indptr[N] = (unsigned)E;
    __syncthreads();
    for (unsigned e = e0 + tid; e < e1; e += 256) {
        unsigned long long pk = packed[e];
        int d = (int)(pk >> 32);
        unsigned p = atomicAdd(&cur[d - n0], 1u);
        ssrc[p] = (unsigned)pk;
    }
}

// ---------------- fused step (r5 verbatim: 32-wide gather MLP, proven 116us) ----------------
__global__ __launch_bounds__(256, 4)
void k_step(float* __restrict__ x, const __hip_bfloat16* __restrict__ m_in,
            __hip_bfloat16* __restrict__ m_out,
            const int* __restrict__ batch,
            const unsigned* __restrict__ indptr, const unsigned* __restrict__ ssrc,
            const float* __restrict__ Wa, const float* __restrict__ xgw,
            const float* __restrict__ Wg, const float* __restrict__ bg,
            const float* __restrict__ Wa1, const float* __restrict__ ba1,
            const float* __restrict__ Wf, const float* __restrict__ bf,
            const float* __restrict__ Wm_nx, const float* __restrict__ bm_nx,
            float* __restrict__ la1, float* __restrict__ U, float* __restrict__ S,
            int N, int hasNext) {
    __shared__ float WL[2048];    // Wa rows 0..31 then 64..95 (row-major, k*32+j)
    __shared__ float WmL[1024];
    __shared__ float zL[8][64];   // [x(32) | agg(32)] per group
    __shared__ float xnL[8][32];
    __shared__ float WgL[32], W1L[32], bmL[32], bfL[32];
    __shared__ float bgL, b1L;
    int tid = threadIdx.x;
    for (int t = tid; t < 2048; t += 256) WL[t] = (t < 1024) ? Wa[t] : Wa[t + 1024];
    if (hasNext) {
        for (int t = tid; t < 1024; t += 256) WmL[t] = Wm_nx[t];
        if (tid < 32) bmL[tid] = bm_nx[tid];
    }
    if (tid < 32) { WgL[tid] = Wg[tid]; W1L[tid] = Wa1[tid]; bfL[tid] = bf[tid]; }
    if (tid == 0) { bgL = bg[0]; b1L = ba1[0]; }
    int s = tid >> 5, j = tid & 31;
    int c = j & 7, eo = j >> 3;
    // Wf column j in registers (global reads, once per kernel; L2-hot)
    float wfr[32];
#pragma unroll
    for (int k = 0; k < 32; ++k) wfr[k] = Wf[k * 32 + j];
    const uint2* m2 = (const uint2*)m_in;
    int nbase = blockIdx.x * NPB;
    int rep = blockIdx.x & (NREP - 1);
    float* Urep = U + (size_t)rep * GG * 32;
    float* Srep = S + (size_t)rep * GG;
    __syncthreads();
    int gcur = -1;
    float Uacc = 0.f, Sacc = 0.f;
    // zL/xnL rows private per 32-lane group -> wave-synchronous LDS, no barriers.
    for (int sub = 0; sub < NPB / 8; ++sub) {
        int n = nbase + sub * 8 + s;
        bool valid = n < N;
        int gb = gcur;
        float xj = 0.f;
        if (valid) {
            xj = x[n * 32 + j];
            zL[s][j] = xj;
            gb = batch[n];
        }
        if (valid && gb != gcur) {
            if (gcur >= 0) {
                atomicAdd(&Urep[gcur * 32 + j], Uacc);
                if (j == 0) atomicAdd(&Srep[gcur], Sacc);
            }
            gcur = gb; Uacc = 0.f; Sacc = 0.f;
        }
        unsigned st = 0, en = 0;
        if (valid) { st = indptr[n]; en = indptr[n + 1]; }
        float a[4];
#pragma unroll
        for (int t = 0; t < 4; ++t) a[t] = -INFINITY;
        if (en > st) {
            unsigned last = en - 1;
            for (unsigned base = st; base < en; base += 32) {
                unsigned eA = min(base + eo, last);
                unsigned eB = min(base + 4 + eo, last);
                unsigned eC = min(base + 8 + eo, last);
                unsigned eD = min(base + 12 + eo, last);
                unsigned eE = min(base + 16 + eo, last);
                unsigned eF = min(base + 20 + eo, last);
                unsigned eG = min(base + 24 + eo, last);
                unsigned eH = min(base + 28 + eo, last);
                unsigned sA = ssrc[eA];
                unsigned sB = ssrc[eB];
                unsigned sC = ssrc[eC];
                unsigned sD = ssrc[eD];
                unsigned sE = ssrc[eE];
                unsigned sF = ssrc[eF];
                unsigned sG = ssrc[eG];
                unsigned sH = ssrc[eH];
                uint2 vA = m2[sA * 8 + c];
                uint2 vB = m2[sB * 8 + c];
                uint2 vC = m2[sC * 8 + c];
                uint2 vD = m2[sD * 8 + c];
                uint2 vE = m2[sE * 8 + c];
                uint2 vF = m2[sF * 8 + c];
                uint2 vG = m2[sG * 8 + c];
                uint2 vH = m2[sH * 8 + c];
                a[0] = fmaxf(a[0], fmaxf(fmaxf(fmaxf(bfLo(vA.x), bfLo(vB.x)), fmaxf(bfLo(vC.x), bfLo(vD.x))),
                                         fmaxf(fmaxf(bfLo(vE.x), bfLo(vF.x)), fmaxf(bfLo(vG.x), bfLo(vH.x)))));
                a[1] = fmaxf(a[1], fmaxf(fmaxf(fmaxf(bfHi(vA.x), bfHi(vB.x)), fmaxf(bfHi(vC.x), bfHi(vD.x))),
                                         fmaxf(fmaxf(bfHi(vE.x), bfHi(vF.x)), fmaxf(bfHi(vG.x), bfHi(vH.x)))));
                a[2] = fmaxf(a[2], fmaxf(fmaxf(fmaxf(bfLo(vA.y), bfLo(vB.y)), fmaxf(bfLo(vC.y), bfLo(vD.y))),
                                         fmaxf(fmaxf(bfLo(vE.y), bfLo(vF.y)), fmaxf(bfLo(vG.y), bfLo(vH.y)))));
                a[3] = fmaxf(a[3], fmaxf(fmaxf(fmaxf(bfHi(vA.y), bfHi(vB.y)), fmaxf(bfHi(vC.y), bfHi(vD.y))),
                                         fmaxf(fmaxf(bfHi(vE.y), bfHi(vF.y)), fmaxf(bfHi(vG.y), bfHi(vH.y)))));
            }
        }
#pragma unroll
        for (int t = 0; t < 4; ++t) {
            a[t] = fmaxf(a[t], __shfl_xor(a[t], 8));
            a[t] = fmaxf(a[t], __shfl_xor(a[t], 16));
        }
        if (valid && eo == 0) {
            bool empty = (st == en);
#pragma unroll
            for (int t = 0; t < 4; ++t)
                zL[s][32 + (c << 2) + t] = empty ? 0.f : a[t];
        }
        if (valid) {
            float acc0 = xgw[gb * 32 + j];
            float acc1 = 0.f;
#pragma unroll
            for (int k = 0; k < 64; k += 2) {
                acc0 += zL[s][k] * WL[k * 32 + j];
                acc1 += zL[s][k + 1] * WL[(k + 1) * 32 + j];
            }
            float xn = lrelu(acc0 + acc1) + xj;
            x[n * 32 + j] = xn;
            xnL[s][j] = xn;
            float lv = xn * WgL[j];
            if (hasNext) {
#pragma unroll
                for (int off = 16; off; off >>= 1) lv += __shfl_xor(lv, off);
            } else {
                float l1 = xn * W1L[j];
#pragma unroll
                for (int off = 16; off; off >>= 1) { lv += __shfl_xor(lv, off); l1 += __shfl_xor(l1, off); }
                if (j == 0) la1[n] = l1 + b1L;
            }
            float e = __expf(lv + bgL);
            float f = bfL[j];
            if (hasNext) {
                float a2 = bmL[j];
#pragma unroll
                for (int k = 0; k < 32; ++k) {
                    float v = xnL[s][k];
                    f += v * wfr[k];
                    a2 += v * WmL[k * 32 + j];
                }
                m_out[n * 32 + j] = __float2bfloat16(lrelu(a2));
            } else {
#pragma unroll
                for (int k = 0; k < 32; ++k) f += xnL[s][k] * wfr[k];
            }
            Uacc += e * lrelu(f);
            Sacc += e;
        }
    }
    if (gcur >= 0) {
        atomicAdd(&Urep[gcur * 32 + j], Uacc);
        if (j == 0) atomicAdd(&Srep[gcur], Sacc);
    }
}

// ---------------- reduce replicas + xg transform + residual + reset + next xgw ------------
// One block per graph; fused final phase (a1 softmax + value + a0 heads) when !hasNext.
__global__ void k_gupd(float* __restrict__ U, float* __restrict__ S,
                       const float* __restrict__ xg_in,
                       const float* __restrict__ Wt, const float* __restrict__ bt,
                       float* __restrict__ xg_out,
                       const float* __restrict__ WaNx, const float* __restrict__ baNx,
                       float* __restrict__ xgw, int hasNext,
                       const float* __restrict__ logits, const int* __restrict__ goff,
                       const void* __restrict__ Wv, const void* __restrict__ bv,
                       const void* __restrict__ Wa0, const void* __restrict__ ba0,
                       void* __restrict__ out, int N, const int* __restrict__ dtf) {
    __shared__ float Up[8][32];
    __shared__ float Sp[8];
    __shared__ float pl[32];
    __shared__ float vL[32];
    __shared__ float red[256];
    int g = blockIdx.x;
    int tid = threadIdx.x;
    int rp = tid >> 5, j = tid & 31;
    float usum = 0.f, ssum = 0.f;
    for (int r = rp; r < NREP; r += 8) {
        size_t ui = (size_t)r * GG * 32 + g * 32 + j;
        usum += U[ui];
        U[ui] = 0.f;   // reset for next step
        if (j == 0) { ssum += S[r * GG + g]; S[r * GG + g] = 0.f; }
    }
    Up[rp][j] = usum;
    if (j == 0) Sp[rp] = ssum;
    __syncthreads();
    if (rp == 0) {
        float ut = 0.f;
#pragma unroll
        for (int i = 0; i < 8; ++i) ut += Up[i][j];
        float st = ((Sp[0] + Sp[1]) + (Sp[2] + Sp[3])) + ((Sp[4] + Sp[5]) + (Sp[6] + Sp[7]));
        float inv = (st > 0.f) ? 1.f / st : 0.f;
        pl[j] = ut * inv;             // wave-synchronous within the 32-lane group
        float xgv = xg_in[g * 32 + j];
        vL[j] = xgv;
        float acc = bt[j];
#pragma unroll
        for (int k = 0; k < 32; ++k) acc += pl[k] * Wt[k * 32 + j];
#pragma unroll
        for (int k = 0; k < 32; ++k) acc += vL[k] * Wt[(32 + k) * 32 + j];
        float v = lrelu(acc) + xgv;
        xg_out[g * 32 + j] = v;
        vL[j] = v;                    // same wave -> ordered; also feeds final phase
        if (hasNext) {
            float aw = baNx[j];
#pragma unroll
            for (int k = 0; k < 32; ++k) aw += vL[k] * WaNx[(32 + k) * 32 + j];
            xgw[g * 32 + j] = aw;
        }
    }
    __syncthreads();
    if (hasNext) return;
    // ---- fused final: a1 softmax over graph g + value + a0 probs ----
    int isf = *dtf;
    int s0 = goff[g], s1 = goff[g + 1];
    float lm = -INFINITY;
    for (int n = s0 + tid; n < s1; n += 256) lm = fmaxf(lm, logits[n]);
    red[tid] = lm;
    __syncthreads();
    for (int off = 128; off; off >>= 1) {
        if (tid < off) red[tid] = fmaxf(red[tid], red[tid + off]);
        __syncthreads();
    }
    float gmax = red[0];
    __syncthreads();
    float ls = 0.f;
    for (int n = s0 + tid; n < s1; n += 256) ls += expf(logits[n] - gmax);
    red[tid] = ls;
    __syncthreads();
    for (int off = 128; off; off >>= 1) {
        if (tid < off) red[tid] += red[tid + off];
        __syncthreads();
    }
    float inv = (red[0] > 0.f) ? 1.f / red[0] : 0.f;
    __syncthreads();
    for (int n = s0 + tid; n < s1; n += 256)
        stf(out, 384 + n, expf(logits[n] - gmax) * inv, isf);
    if (tid == 0) {
        float acc = ldf(bv, 0, isf);
        for (int k = 0; k < 32; ++k) acc += vL[k] * ldf(Wv, k, isf);
        stf(out, g, acc, isf);
        float l0 = ldf(ba0, 0, isf), l1 = ldf(ba0, 1, isf);
        for (int k = 0; k < 32; ++k) {
            float xv = vL[k];
            l0 += xv * ldf(Wa0, k * 2, isf);
            l1 += xv * ldf(Wa0, k * 2 + 1, isf);
        }
        float mm = fmaxf(l0, l1);
        float e0 = expf(l0 - mm), e1 = expf(l1 - mm);
        float si = 1.f / (e0 + e1);
        stf(out, 128 + 2 * g, e0 * si, isf);
        stf(out, 128 + 2 * g + 1, e1 * si, isf);
    }
}

extern "C" void kernel_launch(void* const* d_in, const int* in_sizes, int n_in,
                              void* d_out, int out_size, void* d_ws, size_t ws_size,
                              hipStream_t stream) {
    const void* nf      = d_in[0];
    const int*  eidx    = (const int*)d_in[1];
    const int*  batch   = (const int*)d_in[2];
    const void* W_embed = d_in[4];
    const void* b_embed = d_in[5];
    const void* Wm      = d_in[6];
    const void* bm      = d_in[7];
    const void* Wa      = d_in[8];
    const void* ba      = d_in[9];
    const void* Wgate   = d_in[10];
    const void* bgate   = d_in[11];
    const void* Wfeat   = d_in[12];
    const void* bfeat   = d_in[13];
    const void* Wt      = d_in[14];
    const void* bt      = d_in[15];
    const void* W_v     = d_in[16];
    const void* b_v     = d_in[17];
    const void* W_a0    = d_in[18];
    const void* b_a0    = d_in[19];
    const void* W_a1    = d_in[20];
    const void* b_a1    = d_in[21];

    const int N = in_sizes[0];
    const int E = in_sizes[1] / 2;
    const int nWm = in_sizes[6];  // 3*32*32 = 3072
    const int* src = eidx;
    const int* dst = eidx + E;
    const int B = (N + 255) >> 8;

    char* ws = (char*)d_ws;
    size_t off = 0;
    auto alloc = [&](size_t bytes) -> char* {
        char* p = ws + off;
        off = (off + bytes + 255) & ~(size_t)255;
        return p;
    };
    float*          x      = (float*)alloc((size_t)N * 32 * 4);
    // packed now UN-ALIASED from m buffers so binA can overlap embed (k_work).
    size_t mBytes  = (size_t)N * 32 * 2;
    __hip_bfloat16*     m_a    = (__hip_bfloat16*)alloc(mBytes);
    __hip_bfloat16*     m_b    = (__hip_bfloat16*)alloc(mBytes);
    unsigned long long* packed = (unsigned long long*)alloc((size_t)E * 8);
    float*          la1    = (float*)alloc((size_t)N * 4);
    unsigned*       indptr = (unsigned*)alloc((size_t)(N + 1) * 4);
    unsigned*       cursor = (unsigned*)alloc((size_t)N * 4);
    unsigned*       ssrc   = (unsigned*)alloc((size_t)(E + 16) * 4);
    const int nb = (N + 255) / 256;
    unsigned*       bsum   = (unsigned*)alloc((size_t)nb * 4);
    unsigned*       boff   = (unsigned*)alloc((size_t)nb * 4);
    unsigned*       bcnt   = (unsigned*)alloc((size_t)(B + 1) * 4);
    unsigned*       bbase  = (unsigned*)alloc((size_t)(B + 1) * 4);
    unsigned*       bcur   = (unsigned*)alloc((size_t)(B + 1) * 4);
    int*            goff   = (int*)alloc((size_t)(GG + 1) * 4);
    float*          xg_a   = (float*)alloc((size_t)GG * 32 * 4);
    float*          xg_b   = (float*)alloc((size_t)GG * 32 * 4);
    float*          xgw    = (float*)alloc((size_t)GG * 32 * 4);
    float*          U      = (float*)alloc((size_t)NREP * GG * 32 * 4);
    float*          S      = (float*)alloc((size_t)NREP * GG * 4);
    int*            dtf    = (int*)alloc(256);
    float*          wcat   = (float*)alloc((size_t)WCAT_N * 4);

    const int nB_n  = (N + 255) / 256;
    const int nB_e  = (E + 255) / 256;
    const int nB_n8 = (N + 7) / 8;
    const int nB_st = (N + NPB - 1) / NPB;
    const int nB_ch = (E + CHUNK - 1) / CHUNK;

    // detect dtype + zero bcnt (must precede prep's bhist range)
    k_detect<<<1, 256, 0, stream>>>((const unsigned short*)Wm, nWm, dtf, bcnt, B);

    CvtArgs ca;
    const void* ps[12] = {Wm, bm, Wa, ba, Wgate, bgate, Wfeat, bfeat, Wt, bt, W_a1, b_a1};
    const int  offs[12] = {OFF_Wm, OFF_bm, OFF_Wa, OFF_ba, OFF_Wg, OFF_bg,
                           OFF_Wf, OFF_bf, OFF_Wt, OFF_bt, OFF_Wa1, OFF_ba1};
    const int  ns[12]  = {3072, 96, 9216, 96, 96, 3, 3072, 96, 6144, 96, 32, 1};
    for (int i = 0; i < 12; ++i) { ca.p[i] = ps[i]; ca.off[i] = offs[i]; ca.n[i] = ns[i]; }

    // fused prep: cvt + xgw0 + graph_off + bhist + U/S/xg_a zero-fills
    const int nPrep = 432 + 16 + nB_n + nB_ch + 268;
    k_prep<<<nPrep, 256, 0, stream>>>(ca, wcat, dtf, ba, xgw, batch, goff, N,
                                      dst, bcnt, E, B, xg_a, U, S);

    if (B <= 2048) {
        k_bscan<<<1, 256, 0, stream>>>(bcnt, bbase, bcur, B, E);
        // binA || embed in one launch (independent work)
        k_work<<<nB_ch + nB_n8, 256, 0, stream>>>(src, dst, bcur, packed, E, B, nB_ch,
                                                  nf, W_embed, b_embed,
                                                  wcat + OFF_Wm, wcat + OFF_bm,
                                                  x, m_a, N, dtf);
        k_csr<<<B, 256, 0, stream>>>(packed, bbase, indptr, ssrc, N, E);
    } else {
        hipMemsetAsync(cursor, 0, (size_t)N * 4, stream);
        k_hist<<<nB_e, 256, 0, stream>>>(dst, cursor, E);
        k_scan1<<<nb, 256, 0, stream>>>(cursor, indptr, bsum, N);
        k_scan2<<<1, 256, 0, stream>>>(bsum, boff, nb);
        k_scan3<<<nB_n, 256, 0, stream>>>(indptr, boff, cursor, N, E);
        k_scatter<<<nB_e, 256, 0, stream>>>(src, dst, cursor, ssrc, E);
        // embed only (nbA = 0)
        k_work<<<nB_n8, 256, 0, stream>>>(src, dst, bcur, packed, E, B, 0,
                                          nf, W_embed, b_embed,
                                          wcat + OFF_Wm, wcat + OFF_bm,
                                          x, m_a, N, dtf);
    }

    float* xg_cur = xg_a;
    float* xg_nxt = xg_b;
    __hip_bfloat16* m_cur = m_a;
    __hip_bfloat16* m_nxt = m_b;
    for (int i = 0; i < 3; ++i) {
        int hasNext = (i < 2) ? 1 : 0;
        k_step<<<nB_st, 256, 0, stream>>>(x, m_cur, m_nxt, batch, indptr, ssrc,
                                          wcat + OFF_Wa + i * 3072, xgw,
                                          wcat + OFF_Wg + i * 32, wcat + OFF_bg + i,
                                          wcat + OFF_Wa1, wcat + OFF_ba1,
                                          wcat + OFF_Wf + i * 1024, wcat + OFF_bf + i * 32,
                                          wcat + OFF_Wm + (i + 1) * 1024,
                                          wcat + OFF_bm + (i + 1) * 32,
                                          la1, U, S, N, hasNext);
        k_gupd<<<GG, 256, 0, stream>>>(U, S, xg_cur,
                                       wcat + OFF_Wt + i * 2048,
                                       wcat + OFF_bt + i * 32, xg_nxt,
                                       wcat + OFF_Wa + (i + 1) * 3072,
                                       wcat + OFF_ba + (i + 1) * 32,
                                       xgw, hasNext,
                                       la1, goff, W_v, b_v, W_a0, b_a0,
                                       d_out, N, dtf);
        float* tmp = xg_cur; xg_cur = xg_nxt; xg_nxt = tmp;
        __hip_bfloat16* tm = m_cur; m_cur = m_nxt; m_nxt = tm;
    }
}

// Round 8
// 554.641 us; speedup vs baseline: 1.2654x; 1.0223x over previous
//
#include <hip/hip_runtime.h>
#include <hip/hip_bf16.h>

#define GG 128
#define SLOPE 0.01f
#define CHUNK 8192
#define NPB 64   // nodes per block in k_step
#define NREP 64  // accumulator replicas (atomic contention striping)

// wcat element offsets (f32 staged weights)
#define OFF_Wm   0
#define OFF_bm   3072
#define OFF_Wa   3168
#define OFF_ba   12384
#define OFF_Wg   12480
#define OFF_bg   12576
#define OFF_Wf   12592
#define OFF_bf   15664
#define OFF_Wt   15760
#define OFF_bt   21904
#define OFF_Wa1  22000
#define OFF_ba1  22032
#define WCAT_N   22048

__device__ __forceinline__ float lrelu(float v) { return v > 0.f ? v : SLOPE * v; }

__device__ __forceinline__ float ldf(const void* p, int i, int isf) {
    if (isf) return ((const float*)p)[i];
    return __bfloat162float(((const __hip_bfloat16*)p)[i]);
}
__device__ __forceinline__ void stf(void* p, int i, float v, int isf) {
    if (isf) ((float*)p)[i] = v;
    else ((__hip_bfloat16*)p)[i] = __float2bfloat16(v);
}

// bf16-pair unpack from u32 (bit ops only)
__device__ __forceinline__ float bfLo(unsigned u) { return __uint_as_float(u << 16); }
__device__ __forceinline__ float bfHi(unsigned u) { return __uint_as_float(u & 0xFFFF0000u); }

// ---------------- dtype detection + bcnt zero ----------------
__global__ void k_detect(const unsigned short* __restrict__ w, int n, int* __restrict__ flag,
                         unsigned* __restrict__ bcnt, int B) {
    __shared__ int bad;
    for (int t = threadIdx.x; t <= B; t += 256) bcnt[t] = 0u;
    if (threadIdx.x == 0) bad = 0;
    __syncthreads();
    for (int t = threadIdx.x; t < n; t += 256) {
        unsigned short u = w[t];
        int e = (u >> 7) & 0xFF;
        if (e >= 141) bad = 1;  // benign same-value race
    }
    __syncthreads();
    if (threadIdx.x == 0) { flag[0] = bad; flag[32] = 1; }
}

// ---------------- fused prep: cvt + xgw0 + graph_off + bhist + zero-fills ----------------
struct CvtArgs {
    const void* p[12];
    int off[12];
    int n[12];
};
// block ranges: [0,432) cvt | [432,448) xgw0 | [..,+cG) graph_off | [..,+cH) bhist | [..,+268) fills
__global__ void k_prep(CvtArgs a, float* __restrict__ wcat, const int* __restrict__ dtf,
                       const void* __restrict__ ba0, float* __restrict__ xgw,
                       const int* __restrict__ batch, int* __restrict__ goff, int N,
                       const int* __restrict__ dst, unsigned* __restrict__ bcnt, int E, int B,
                       float* __restrict__ xg_a, float* __restrict__ U, float* __restrict__ S) {
    __shared__ unsigned h[2048];
    int blk = blockIdx.x;
    int tid = threadIdx.x;
    const int cG = (N + 255) >> 8;
    const int cH = (E + CHUNK - 1) / CHUNK;
    if (blk < 432) {  // weight staging to f32
        int seg = blk / 36;
        int i = (blk % 36) * 256 + tid;
        int isf = *dtf;
        if (i < a.n[seg]) wcat[a.off[seg] + i] = ldf(a.p[seg], i, isf);
        return;
    }
    blk -= 432;
    if (blk < 16) {   // step-0 xgw = ba0 broadcast
        int isf = *dtf;
        int idx = blk * 256 + tid;
        xgw[idx] = ldf(ba0, idx & 31, isf);
        return;
    }
    blk -= 16;
    if (blk < cG) {   // graph offsets from sorted batch
        int n = blk * 256 + tid;
        if (n >= N) return;
        int bn = batch[n];
        if (n == 0) {
            for (int g = 0; g <= bn; ++g) goff[g] = 0;
        } else {
            int bp = batch[n - 1];
            for (int g = bp + 1; g <= bn; ++g) goff[g] = n;
        }
        if (n == N - 1) {
            for (int g = bn + 1; g <= GG; ++g) goff[g] = N;
        }
        return;
    }
    blk -= cG;
    if (blk < cH) {   // bucket histogram (bucketed path only)
        if (B > 2048) return;
        for (int t = tid; t < B; t += 256) h[t] = 0;
        __syncthreads();
        int start = blk * CHUNK, end = min(E, start + CHUNK);
        for (int e = start + tid; e < end; e += 256)
            atomicAdd(&h[dst[e] >> 8], 1u);
        __syncthreads();
        for (int t = tid; t < B; t += 256)
            if (h[t]) atomicAdd(&bcnt[t], h[t]);
        return;
    }
    blk -= cH;
    {   // zero fills: U (65536 f4) | S (2048 f4) | xg_a (1024 f4)
        float4 z4 = make_float4(0.f, 0.f, 0.f, 0.f);
        long long fi = (long long)blk * 256 + tid;
        if (fi < 65536) { ((float4*)U)[fi] = z4; return; }
        fi -= 65536;
        if (fi < 2048) { ((float4*)S)[fi] = z4; return; }
        fi -= 2048;
        if (fi < 1024) { ((float4*)xg_a)[fi] = z4; return; }
    }
}

// ---------------- fallback CSR build (B > 2048 only) ----------------
__global__ void k_hist(const int* __restrict__ dst, unsigned* __restrict__ deg, int E) {
    int e = blockIdx.x * 256 + threadIdx.x;
    if (e >= E) return;
    atomicAdd(&deg[dst[e]], 1u);
}
__global__ void k_scan1(const unsigned* __restrict__ deg, unsigned* __restrict__ excl,
                        unsigned* __restrict__ bsum, int N) {
    __shared__ unsigned s[256];
    int i = blockIdx.x * 256 + threadIdx.x;
    unsigned v = (i < N) ? deg[i] : 0u;
    s[threadIdx.x] = v;
    __syncthreads();
    for (int off = 1; off < 256; off <<= 1) {
        unsigned t = (threadIdx.x >= (unsigned)off) ? s[threadIdx.x - off] : 0u;
        __syncthreads();
        s[threadIdx.x] += t;
        __syncthreads();
    }
    if (i < N) excl[i] = s[threadIdx.x] - v;
    if (threadIdx.x == 255) bsum[blockIdx.x] = s[255];
}
__global__ void k_scan2(const unsigned* __restrict__ bsum, unsigned* __restrict__ boff, int nb) {
    __shared__ unsigned s[256];
    __shared__ unsigned carry;
    if (threadIdx.x == 0) carry = 0u;
    __syncthreads();
    for (int base = 0; base < nb; base += 256) {
        int i = base + threadIdx.x;
        unsigned v = (i < nb) ? bsum[i] : 0u;
        s[threadIdx.x] = v;
        __syncthreads();
        for (int off = 1; off < 256; off <<= 1) {
            unsigned t = (threadIdx.x >= (unsigned)off) ? s[threadIdx.x - off] : 0u;
            __syncthreads();
            s[threadIdx.x] += t;
            __syncthreads();
        }
        if (i < nb) boff[i] = carry + s[threadIdx.x] - v;
        __syncthreads();
        if (threadIdx.x == 0) carry += s[255];
        __syncthreads();
    }
}
__global__ void k_scan3(unsigned* __restrict__ indptr, const unsigned* __restrict__ boff,
                        unsigned* __restrict__ cursor, int N, int E) {
    int i = blockIdx.x * 256 + threadIdx.x;
    if (i >= N) return;
    unsigned v = indptr[i] + boff[i >> 8];
    indptr[i] = v;
    cursor[i] = v;
    if (i == 0) indptr[N] = (unsigned)E;
}
__global__ void k_scatter(const int* __restrict__ src, const int* __restrict__ dst,
                          unsigned* __restrict__ cursor, unsigned* __restrict__ ssrc, int E) {
    int e = blockIdx.x * 256 + threadIdx.x;
    if (e >= E) return;
    unsigned pos = atomicAdd(&cursor[dst[e]], 1u);
    ssrc[pos] = (unsigned)src[e];
}

// ---------------- bucketed scan ----------------
__global__ void k_bscan(const unsigned* __restrict__ bcnt, unsigned* __restrict__ bbase,
                        unsigned* __restrict__ bcur, int B, int E) {
    __shared__ unsigned s[256];
    __shared__ unsigned carry;
    if (threadIdx.x == 0) carry = 0u;
    __syncthreads();
    for (int base = 0; base < B; base += 256) {
        int i = base + threadIdx.x;
        unsigned v = (i < B) ? bcnt[i] : 0u;
        s[threadIdx.x] = v;
        __syncthreads();
        for (int off = 1; off < 256; off <<= 1) {
            unsigned t = (threadIdx.x >= (unsigned)off) ? s[threadIdx.x - off] : 0u;
            __syncthreads();
            s[threadIdx.x] += t;
            __syncthreads();
        }
        if (i < B) {
            unsigned ex = carry + s[threadIdx.x] - v;
            bbase[i] = ex;
            bcur[i] = ex;
        }
        __syncthreads();
        if (threadIdx.x == 0) carry += s[255];
        __syncthreads();
    }
    if (threadIdx.x == 0) bbase[B] = (unsigned)E;
}

// ---------------- fused work: binA (bucket binning) || embed+step-0 message ----------------
// binA blocks [0,nbA); embed blocks [nbA, nbA+nbE). Independent work, one launch.
__global__ void k_work(const int* __restrict__ src, const int* __restrict__ dst,
                       unsigned* __restrict__ bcur, unsigned long long* __restrict__ packed,
                       int E, int B, int nbA,
                       const void* __restrict__ nf, const void* __restrict__ We,
                       const void* __restrict__ be,
                       const float* __restrict__ Wm0, const float* __restrict__ bm0,
                       float* __restrict__ x, __hip_bfloat16* __restrict__ m, int N,
                       const int* __restrict__ dtf) {
    __shared__ unsigned h[2048];
    __shared__ unsigned pos[2048];
    __shared__ float WL[1024];
    __shared__ float WeL[32], beL[32], bmL[32];
    __shared__ float xs[8][32];
    int tid = threadIdx.x;
    if ((int)blockIdx.x < nbA) {
        // ---- binA ----
        for (int t = tid; t < B; t += 256) h[t] = 0;
        __syncthreads();
        int start = blockIdx.x * CHUNK, end = min(E, start + CHUNK);
        for (int e = start + tid; e < end; e += 256)
            atomicAdd(&h[dst[e] >> 8], 1u);
        __syncthreads();
        for (int t = tid; t < B; t += 256)
            pos[t] = h[t] ? atomicAdd(&bcur[t], h[t]) : 0u;
        __syncthreads();
        for (int e = start + tid; e < end; e += 256) {
            int d = dst[e];
            unsigned p = atomicAdd(&pos[d >> 8], 1u);
            packed[p] = ((unsigned long long)(unsigned)d << 32) | (unsigned)src[e];
        }
        return;
    }
    // ---- embed + step-0 message ----
    int blkE = blockIdx.x - nbA;
    int isf = *dtf;
    for (int t = tid; t < 1024; t += 256) WL[t] = Wm0[t];
    if (tid < 32) { WeL[tid] = ldf(We, tid, isf); beL[tid] = ldf(be, tid, isf); bmL[tid] = bm0[tid]; }
    int s = tid >> 5, j = tid & 31;
    int n = blkE * 8 + s;
    __syncthreads();
    float xv = 0.f;
    if (n < N) {
        xv = lrelu(ldf(nf, n, isf) * WeL[j] + beL[j]);
        x[n * 32 + j] = xv;
        xs[s][j] = xv;
    }
    __syncthreads();
    if (n >= N) return;
    float acc = bmL[j];
#pragma unroll
    for (int k = 0; k < 32; ++k) acc += xs[s][k] * WL[k * 32 + j];
    m[n * 32 + j] = __float2bfloat16(lrelu(acc));
}

// per-bucket: LDS degree count + scan -> indptr, then bucket-local scatter
__global__ void k_csr(const unsigned long long* __restrict__ packed,
                      const unsigned* __restrict__ bbase,
                      unsigned* __restrict__ indptr,
                      unsigned* __restrict__ ssrc, int N, int E) {
    __shared__ unsigned deg[256];
    __shared__ unsigned scn[256];
    __shared__ unsigned cur[256];
    int g = blockIdx.x, tid = threadIdx.x;
    int n0 = g << 8;
    int cnt = min(256, N - n0);
    deg[tid] = 0;
    __syncthreads();
    unsigned e0 = bbase[g], e1 = bbase[g + 1];
    for (unsigned e = e0 + tid; e < e1; e += 256) {
        int d = (int)(packed[e] >> 32);
        atomicAdd(&deg[d - n0], 1u);
    }
    __syncthreads();
    unsigned v = deg[tid];
    scn[tid] = v;
    __syncthreads();
    for (int off = 1; off < 256; off <<= 1) {
        unsigned t = (tid >= off) ? scn[tid - off] : 0u;
        __syncthreads();
        scn[tid] += t;
        __syncthreads();
    }
    unsigned start = e0 + scn[tid] - v;
    if (tid < cnt) { indptr[n0 + tid] = start; cur[tid] = start; }
    if (g == (int)gridDim.x - 1 && tid == 0) indptr[N] = (unsigned)E;
    __syncthreads();
    for (unsigned e = e0 + tid; e < e1; e += 256) {
        unsigned long long pk = packed[e];
        int d = (int)(pk >> 32);
        unsigned p = atomicAdd(&cur[d - n0], 1u);
        ssrc[p] = (unsigned)pk;
    }
}

// ---------------- fused step (round-8: r5 body + light ssrc prefetch) ----------------
// r6's full 2-deep pipeline spilled (~50 rotated VGPRs -> scratch, WRITE_SIZE 2x).
// This light version prefetches ONLY the first 2 chain levels: during node sub's
// compute, issue ssrc(sub+1) (its indptr arrived last iter) and meta(sub+2).
// At iter start the m-loads fire immediately from resident ssrc regs -> exposed
// latency per node drops from (indptr+ssrc+m ~1000cy) to (m ~500cy).
// State added vs r5: 8 ssrc regs + 6 meta scalars (~+20 VGPR, no in-flight m regs).
__global__ __launch_bounds__(256, 4)
void k_step(float* __restrict__ x, const __hip_bfloat16* __restrict__ m_in,
            __hip_bfloat16* __restrict__ m_out,
            const int* __restrict__ batch,
            const unsigned* __restrict__ indptr, const unsigned* __restrict__ ssrc,
            const float* __restrict__ Wa, const float* __restrict__ xgw,
            const float* __restrict__ Wg, const float* __restrict__ bg,
            const float* __restrict__ Wa1, const float* __restrict__ ba1,
            const float* __restrict__ Wf, const float* __restrict__ bf,
            const float* __restrict__ Wm_nx, const float* __restrict__ bm_nx,
            float* __restrict__ la1, float* __restrict__ U, float* __restrict__ S,
            int N, int hasNext) {
    __shared__ float WL[2048];    // Wa rows 0..31 then 64..95 (row-major, k*32+j)
    __shared__ float WmL[1024];
    __shared__ float zL[8][64];   // [x(32) | agg(32)] per group
    __shared__ float xnL[8][32];
    __shared__ float WgL[32], W1L[32], bmL[32], bfL[32];
    __shared__ float bgL, b1L;
    int tid = threadIdx.x;
    for (int t = tid; t < 2048; t += 256) WL[t] = (t < 1024) ? Wa[t] : Wa[t + 1024];
    if (hasNext) {
        for (int t = tid; t < 1024; t += 256) WmL[t] = Wm_nx[t];
        if (tid < 32) bmL[tid] = bm_nx[tid];
    }
    if (tid < 32) { WgL[tid] = Wg[tid]; W1L[tid] = Wa1[tid]; bfL[tid] = bf[tid]; }
    if (tid == 0) { bgL = bg[0]; b1L = ba1[0]; }
    int s = tid >> 5, j = tid & 31;
    int c = j & 7, eo = j >> 3;
    // Wf column j in registers (global reads, once per kernel; L2-hot)
    float wfr[32];
#pragma unroll
    for (int k = 0; k < 32; ++k) wfr[k] = Wf[k * 32 + j];
    const uint2* m2 = (const uint2*)m_in;
    int nbase = blockIdx.x * NPB;
    int rep = blockIdx.x & (NREP - 1);
    float* Urep = U + (size_t)rep * GG * 32;
    float* Srep = S + (size_t)rep * GG;
    __syncthreads();
    int gcur = -1;
    float Uacc = 0.f, Sacc = 0.f;

    // ---- prefetch state ----
    int nC; bool vC; int gbC; float xjC; unsigned stC, enC;   // current node (fully resolved)
    int nN; bool vN; int gbN; float xjN; unsigned stN, enN;   // next node meta
    unsigned p0, p1, p2, p3, p4, p5, p6, p7;                  // ssrc of current (resident)
    unsigned q0, q1, q2, q3, q4, q5, q6, q7;                  // ssrc of next (in flight)

    auto loadMeta = [&](int sub, int& nn, bool& vv, int& gg, float& xx,
                        unsigned& st_, unsigned& en_) {
        int n = nbase + sub * 8 + s;
        vv = (n < N);
        int cl = vv ? n : (N - 1);
        nn = cl;
        xx = x[cl * 32 + j];
        gg = batch[cl];
        st_ = indptr[cl];
        en_ = indptr[cl + 1];
    };
    auto issueSS = [&](unsigned st_, unsigned en_,
                       unsigned& a0, unsigned& a1, unsigned& a2, unsigned& a3,
                       unsigned& a4, unsigned& a5, unsigned& a6, unsigned& a7) {
        unsigned b = (en_ > st_) ? st_ : 0u;
        unsigned last = (en_ > st_) ? (en_ - 1) : 0u;
        a0 = ssrc[min(b + eo, last)];
        a1 = ssrc[min(b + 4 + eo, last)];
        a2 = ssrc[min(b + 8 + eo, last)];
        a3 = ssrc[min(b + 12 + eo, last)];
        a4 = ssrc[min(b + 16 + eo, last)];
        a5 = ssrc[min(b + 20 + eo, last)];
        a6 = ssrc[min(b + 24 + eo, last)];
        a7 = ssrc[min(b + 28 + eo, last)];
    };

    // prologue: meta(0) -> ssrc(0); meta(1)
    loadMeta(0, nC, vC, gbC, xjC, stC, enC);
    issueSS(stC, enC, p0, p1, p2, p3, p4, p5, p6, p7);
    loadMeta(1, nN, vN, gbN, xjN, stN, enN);

    for (int sub = 0; sub < NPB / 8; ++sub) {
        // 1. m loads for current node — ssrc regs already resident, fire immediately
        uint2 vA = m2[p0 * 8 + c];
        uint2 vB = m2[p1 * 8 + c];
        uint2 vC2 = m2[p2 * 8 + c];
        uint2 vD = m2[p3 * 8 + c];
        uint2 vE = m2[p4 * 8 + c];
        uint2 vF = m2[p5 * 8 + c];
        uint2 vG = m2[p6 * 8 + c];
        uint2 vH = m2[p7 * 8 + c];
        // 2. prefetch: ssrc(next) from resident stN/enN; meta(sub+2)
        issueSS(stN, enN, q0, q1, q2, q3, q4, q5, q6, q7);
        int nN2; bool vN2; int gbN2; float xjN2; unsigned stN2, enN2;
        loadMeta(sub + 2, nN2, vN2, gbN2, xjN2, stN2, enN2);
        // 3. fmax over the 32 prefetched edges
        float a0 = fmaxf(fmaxf(fmaxf(bfLo(vA.x), bfLo(vB.x)), fmaxf(bfLo(vC2.x), bfLo(vD.x))),
                         fmaxf(fmaxf(bfLo(vE.x), bfLo(vF.x)), fmaxf(bfLo(vG.x), bfLo(vH.x))));
        float a1 = fmaxf(fmaxf(fmaxf(bfHi(vA.x), bfHi(vB.x)), fmaxf(bfHi(vC2.x), bfHi(vD.x))),
                         fmaxf(fmaxf(bfHi(vE.x), bfHi(vF.x)), fmaxf(bfHi(vG.x), bfHi(vH.x))));
        float a2 = fmaxf(fmaxf(fmaxf(bfLo(vA.y), bfLo(vB.y)), fmaxf(bfLo(vC2.y), bfLo(vD.y))),
                         fmaxf(fmaxf(bfLo(vE.y), bfLo(vF.y)), fmaxf(bfLo(vG.y), bfLo(vH.y))));
        float a3 = fmaxf(fmaxf(fmaxf(bfHi(vA.y), bfHi(vB.y)), fmaxf(bfHi(vC2.y), bfHi(vD.y))),
                         fmaxf(fmaxf(bfHi(vE.y), bfHi(vF.y)), fmaxf(bfHi(vG.y), bfHi(vH.y))));
        // rare deg>32 tail: serial gather (uniform branch per 32-lane group)
        if (enC > stC + 32) {
            unsigned last = enC - 1;
            for (unsigned base = stC + 32; base < enC; base += 32) {
                unsigned tA = ssrc[min(base + eo, last)];
                unsigned tB = ssrc[min(base + 4 + eo, last)];
                unsigned tC = ssrc[min(base + 8 + eo, last)];
                unsigned tD = ssrc[min(base + 12 + eo, last)];
                unsigned tE = ssrc[min(base + 16 + eo, last)];
                unsigned tF = ssrc[min(base + 20 + eo, last)];
                unsigned tG = ssrc[min(base + 24 + eo, last)];
                unsigned tH = ssrc[min(base + 28 + eo, last)];
                uint2 wA = m2[tA * 8 + c];
                uint2 wB = m2[tB * 8 + c];
                uint2 wC = m2[tC * 8 + c];
                uint2 wD = m2[tD * 8 + c];
                uint2 wE = m2[tE * 8 + c];
                uint2 wF = m2[tF * 8 + c];
                uint2 wG = m2[tG * 8 + c];
                uint2 wH = m2[tH * 8 + c];
                a0 = fmaxf(a0, fmaxf(fmaxf(fmaxf(bfLo(wA.x), bfLo(wB.x)), fmaxf(bfLo(wC.x), bfLo(wD.x))),
                                     fmaxf(fmaxf(bfLo(wE.x), bfLo(wF.x)), fmaxf(bfLo(wG.x), bfLo(wH.x)))));
                a1 = fmaxf(a1, fmaxf(fmaxf(fmaxf(bfHi(wA.x), bfHi(wB.x)), fmaxf(bfHi(wC.x), bfHi(wD.x))),
                                     fmaxf(fmaxf(bfHi(wE.x), bfHi(wF.x)), fmaxf(bfHi(wG.x), bfHi(wH.x)))));
                a2 = fmaxf(a2, fmaxf(fmaxf(fmaxf(bfLo(wA.y), bfLo(wB.y)), fmaxf(bfLo(wC.y), bfLo(wD.y))),
                                     fmaxf(fmaxf(bfLo(wE.y), bfLo(wF.y)), fmaxf(bfLo(wG.y), bfLo(wH.y)))));
                a3 = fmaxf(a3, fmaxf(fmaxf(fmaxf(bfHi(wA.y), bfHi(wB.y)), fmaxf(bfHi(wC.y), bfHi(wD.y))),
                                     fmaxf(fmaxf(bfHi(wE.y), bfHi(wF.y)), fmaxf(bfHi(wG.y), bfHi(wH.y)))));
            }
        }
        // 4. reduce + compute of current node (covers prefetch latency)
        a0 = fmaxf(a0, __shfl_xor(a0, 8));
        a0 = fmaxf(a0, __shfl_xor(a0, 16));
        a1 = fmaxf(a1, __shfl_xor(a1, 8));
        a1 = fmaxf(a1, __shfl_xor(a1, 16));
        a2 = fmaxf(a2, __shfl_xor(a2, 8));
        a2 = fmaxf(a2, __shfl_xor(a2, 16));
        a3 = fmaxf(a3, __shfl_xor(a3, 8));
        a3 = fmaxf(a3, __shfl_xor(a3, 16));
        if (vC) {
            if (gbC != gcur) {
                if (gcur >= 0) {
                    atomicAdd(&Urep[gcur * 32 + j], Uacc);
                    if (j == 0) atomicAdd(&Srep[gcur], Sacc);
                }
                gcur = gbC; Uacc = 0.f; Sacc = 0.f;
            }
            zL[s][j] = xjC;
            if (eo == 0) {
                bool empty = (stC == enC);
                zL[s][32 + (c << 2) + 0] = empty ? 0.f : a0;
                zL[s][32 + (c << 2) + 1] = empty ? 0.f : a1;
                zL[s][32 + (c << 2) + 2] = empty ? 0.f : a2;
                zL[s][32 + (c << 2) + 3] = empty ? 0.f : a3;
            }
            float acc0 = xgw[gbC * 32 + j];
            float acc1 = 0.f;
#pragma unroll
            for (int k = 0; k < 64; k += 2) {
                acc0 += zL[s][k] * WL[k * 32 + j];
                acc1 += zL[s][k + 1] * WL[(k + 1) * 32 + j];
            }
            float xn = lrelu(acc0 + acc1) + xjC;
            x[nC * 32 + j] = xn;
            xnL[s][j] = xn;
            float lv = xn * WgL[j];
            if (hasNext) {
#pragma unroll
                for (int off = 16; off; off >>= 1) lv += __shfl_xor(lv, off);
            } else {
                float l1 = xn * W1L[j];
#pragma unroll
                for (int off = 16; off; off >>= 1) { lv += __shfl_xor(lv, off); l1 += __shfl_xor(l1, off); }
                if (j == 0) la1[nC] = l1 + b1L;
            }
            float e = __expf(lv + bgL);
            float f = bfL[j];
            if (hasNext) {
                float a2m = bmL[j];
#pragma unroll
                for (int k = 0; k < 32; ++k) {
                    float v = xnL[s][k];
                    f += v * wfr[k];
                    a2m += v * WmL[k * 32 + j];
                }
                m_out[nC * 32 + j] = __float2bfloat16(lrelu(a2m));
            } else {
#pragma unroll
                for (int k = 0; k < 32; ++k) f += xnL[s][k] * wfr[k];
            }
            Uacc += e * lrelu(f);
            Sacc += e;
        }
        // 5. rotate
        nC = nN; vC = vN; gbC = gbN; xjC = xjN; stC = stN; enC = enN;
        nN = nN2; vN = vN2; gbN = gbN2; xjN = xjN2; stN = stN2; enN = enN2;
        p0 = q0; p1 = q1; p2 = q2; p3 = q3; p4 = q4; p5 = q5; p6 = q6; p7 = q7;
    }
    if (gcur >= 0) {
        atomicAdd(&Urep[gcur * 32 + j], Uacc);
        if (j == 0) atomicAdd(&Srep[gcur], Sacc);
    }
}

// ---------------- reduce replicas + xg transform + residual + reset + next xgw ------------
// One block per graph; fused final phase (a1 softmax + value + a0 heads) when !hasNext.
__global__ void k_gupd(float* __restrict__ U, float* __restrict__ S,
                       const float* __restrict__ xg_in,
                       const float* __restrict__ Wt, const float* __restrict__ bt,
                       float* __restrict__ xg_out,
                       const float* __restrict__ WaNx, const float* __restrict__ baNx,
                       float* __restrict__ xgw, int hasNext,
                       const float* __restrict__ logits, const int* __restrict__ goff,
                       const void* __restrict__ Wv, const void* __restrict__ bv,
                       const void* __restrict__ Wa0, const void* __restrict__ ba0,
                       void* __restrict__ out, int N, const int* __restrict__ dtf) {
    __shared__ float Up[8][32];
    __shared__ float Sp[8];
    __shared__ float pl[32];
    __shared__ float vL[32];
    __shared__ float red[256];
    int g = blockIdx.x;
    int tid = threadIdx.x;
    int rp = tid >> 5, j = tid & 31;
    float usum = 0.f, ssum = 0.f;
    for (int r = rp; r < NREP; r += 8) {
        size_t ui = (size_t)r * GG * 32 + g * 32 + j;
        usum += U[ui];
        U[ui] = 0.f;   // reset for next step
        if (j == 0) { ssum += S[r * GG + g]; S[r * GG + g] = 0.f; }
    }
    Up[rp][j] = usum;
    if (j == 0) Sp[rp] = ssum;
    __syncthreads();
    if (rp == 0) {
        float ut = 0.f;
#pragma unroll
        for (int i = 0; i < 8; ++i) ut += Up[i][j];
        float st = ((Sp[0] + Sp[1]) + (Sp[2] + Sp[3])) + ((Sp[4] + Sp[5]) + (Sp[6] + Sp[7]));
        float inv = (st > 0.f) ? 1.f / st : 0.f;
        pl[j] = ut * inv;             // wave-synchronous within the 32-lane group
        float xgv = xg_in[g * 32 + j];
        vL[j] = xgv;
        float acc = bt[j];
#pragma unroll
        for (int k = 0; k < 32; ++k) acc += pl[k] * Wt[k * 32 + j];
#pragma unroll
        for (int k = 0; k < 32; ++k) acc += vL[k] * Wt[(32 + k) * 32 + j];
        float v = lrelu(acc) + xgv;
        xg_out[g * 32 + j] = v;
        vL[j] = v;                    // same wave -> ordered; also feeds final phase
        if (hasNext) {
            float aw = baNx[j];
#pragma unroll
            for (int k = 0; k < 32; ++k) aw += vL[k] * WaNx[(32 + k) * 32 + j];
            xgw[g * 32 + j] = aw;
        }
    }
    __syncthreads();
    if (hasNext) return;
    // ---- fused final: a1 softmax over graph g + value + a0 probs ----
    int isf = *dtf;
    int s0 = goff[g], s1 = goff[g + 1];
    float lm = -INFINITY;
    for (int n = s0 + tid; n < s1; n += 256) lm = fmaxf(lm, logits[n]);
    red[tid] = lm;
    __syncthreads();
    for (int off = 128; off; off >>= 1) {
        if (tid < off) red[tid] = fmaxf(red[tid], red[tid + off]);
        __syncthreads();
    }
    float gmax = red[0];
    __syncthreads();
    float ls = 0.f;
    for (int n = s0 + tid; n < s1; n += 256) ls += expf(logits[n] - gmax);
    red[tid] = ls;
    __syncthreads();
    for (int off = 128; off; off >>= 1) {
        if (tid < off) red[tid] += red[tid + off];
        __syncthreads();
    }
    float inv = (red[0] > 0.f) ? 1.f / red[0] : 0.f;
    __syncthreads();
    for (int n = s0 + tid; n < s1; n += 256)
        stf(out, 384 + n, expf(logits[n] - gmax) * inv, isf);
    if (tid == 0) {
        float acc = ldf(bv, 0, isf);
        for (int k = 0; k < 32; ++k) acc += vL[k] * ldf(Wv, k, isf);
        stf(out, g, acc, isf);
        float l0 = ldf(ba0, 0, isf), l1 = ldf(ba0, 1, isf);
        for (int k = 0; k < 32; ++k) {
            float xv = vL[k];
            l0 += xv * ldf(Wa0, k * 2, isf);
            l1 += xv * ldf(Wa0, k * 2 + 1, isf);
        }
        float mm = fmaxf(l0, l1);
        float e0 = expf(l0 - mm), e1 = expf(l1 - mm);
        float si = 1.f / (e0 + e1);
        stf(out, 128 + 2 * g, e0 * si, isf);
        stf(out, 128 + 2 * g + 1, e1 * si, isf);
    }
}

extern "C" void kernel_launch(void* const* d_in, const int* in_sizes, int n_in,
                              void* d_out, int out_size, void* d_ws, size_t ws_size,
                              hipStream_t stream) {
    const void* nf      = d_in[0];
    const int*  eidx    = (const int*)d_in[1];
    const int*  batch   = (const int*)d_in[2];
    const void* W_embed = d_in[4];
    const void* b_embed = d_in[5];
    const void* Wm      = d_in[6];
    const void* bm      = d_in[7];
    const void* Wa      = d_in[8];
    const void* ba      = d_in[9];
    const void* Wgate   = d_in[10];
    const void* bgate   = d_in[11];
    const void* Wfeat   = d_in[12];
    const void* bfeat   = d_in[13];
    const void* Wt      = d_in[14];
    const void* bt      = d_in[15];
    const void* W_v     = d_in[16];
    const void* b_v     = d_in[17];
    const void* W_a0    = d_in[18];
    const void* b_a0    = d_in[19];
    const void* W_a1    = d_in[20];
    const void* b_a1    = d_in[21];

    const int N = in_sizes[0];
    const int E = in_sizes[1] / 2;
    const int nWm = in_sizes[6];  // 3*32*32 = 3072
    const int* src = eidx;
    const int* dst = eidx + E;
    const int B = (N + 255) >> 8;

    char* ws = (char*)d_ws;
    size_t off = 0;
    auto alloc = [&](size_t bytes) -> char* {
        char* p = ws + off;
        off = (off + bytes + 255) & ~(size_t)255;
        return p;
    };
    float*          x      = (float*)alloc((size_t)N * 32 * 4);
    size_t mBytes  = (size_t)N * 32 * 2;
    __hip_bfloat16*     m_a    = (__hip_bfloat16*)alloc(mBytes);
    __hip_bfloat16*     m_b    = (__hip_bfloat16*)alloc(mBytes);
    unsigned long long* packed = (unsigned long long*)alloc((size_t)E * 8);
    float*          la1    = (float*)alloc((size_t)N * 4);
    unsigned*       indptr = (unsigned*)alloc((size_t)(N + 1) * 4);
    unsigned*       cursor = (unsigned*)alloc((size_t)N * 4);
    unsigned*       ssrc   = (unsigned*)alloc((size_t)(E + 16) * 4);
    const int nb = (N + 255) / 256;
    unsigned*       bsum   = (unsigned*)alloc((size_t)nb * 4);
    unsigned*       boff   = (unsigned*)alloc((size_t)nb * 4);
    unsigned*       bcnt   = (unsigned*)alloc((size_t)(B + 1) * 4);
    unsigned*       bbase  = (unsigned*)alloc((size_t)(B + 1) * 4);
    unsigned*       bcur   = (unsigned*)alloc((size_t)(B + 1) * 4);
    int*            goff   = (int*)alloc((size_t)(GG + 1) * 4);
    float*          xg_a   = (float*)alloc((size_t)GG * 32 * 4);
    float*          xg_b   = (float*)alloc((size_t)GG * 32 * 4);
    float*          xgw    = (float*)alloc((size_t)GG * 32 * 4);
    float*          U      = (float*)alloc((size_t)NREP * GG * 32 * 4);
    float*          S      = (float*)alloc((size_t)NREP * GG * 4);
    int*            dtf    = (int*)alloc(256);
    float*          wcat   = (float*)alloc((size_t)WCAT_N * 4);

    const int nB_n  = (N + 255) / 256;
    const int nB_e  = (E + 255) / 256;
    const int nB_n8 = (N + 7) / 8;
    const int nB_st = (N + NPB - 1) / NPB;
    const int nB_ch = (E + CHUNK - 1) / CHUNK;

    // detect dtype + zero bcnt (must precede prep's bhist range)
    k_detect<<<1, 256, 0, stream>>>((const unsigned short*)Wm, nWm, dtf, bcnt, B);

    CvtArgs ca;
    const void* ps[12] = {Wm, bm, Wa, ba, Wgate, bgate, Wfeat, bfeat, Wt, bt, W_a1, b_a1};
    const int  offs[12] = {OFF_Wm, OFF_bm, OFF_Wa, OFF_ba, OFF_Wg, OFF_bg,
                           OFF_Wf, OFF_bf, OFF_Wt, OFF_bt, OFF_Wa1, OFF_ba1};
    const int  ns[12]  = {3072, 96, 9216, 96, 96, 3, 3072, 96, 6144, 96, 32, 1};
    for (int i = 0; i < 12; ++i) { ca.p[i] = ps[i]; ca.off[i] = offs[i]; ca.n[i] = ns[i]; }

    // fused prep: cvt + xgw0 + graph_off + bhist + U/S/xg_a zero-fills
    const int nPrep = 432 + 16 + nB_n + nB_ch + 268;
    k_prep<<<nPrep, 256, 0, stream>>>(ca, wcat, dtf, ba, xgw, batch, goff, N,
                                      dst, bcnt, E, B, xg_a, U, S);

    if (B <= 2048) {
        k_bscan<<<1, 256, 0, stream>>>(bcnt, bbase, bcur, B, E);
        // binA || embed in one launch (independent work)
        k_work<<<nB_ch + nB_n8, 256, 0, stream>>>(src, dst, bcur, packed, E, B, nB_ch,
                                                  nf, W_embed, b_embed,
                                                  wcat + OFF_Wm, wcat + OFF_bm,
                                                  x, m_a, N, dtf);
        k_csr<<<B, 256, 0, stream>>>(packed, bbase, indptr, ssrc, N, E);
    } else {
        hipMemsetAsync(cursor, 0, (size_t)N * 4, stream);
        k_hist<<<nB_e, 256, 0, stream>>>(dst, cursor, E);
        k_scan1<<<nb, 256, 0, stream>>>(cursor, indptr, bsum, N);
        k_scan2<<<1, 256, 0, stream>>>(bsum, boff, nb);
        k_scan3<<<nB_n, 256, 0, stream>>>(indptr, boff, cursor, N, E);
        k_scatter<<<nB_e, 256, 0, stream>>>(src, dst, cursor, ssrc, E);
        // embed only (nbA = 0)
        k_work<<<nB_n8, 256, 0, stream>>>(src, dst, bcur, packed, E, B, 0,
                                          nf, W_embed, b_embed,
                                          wcat + OFF_Wm, wcat + OFF_bm,
                                          x, m_a, N, dtf);
    }

    float* xg_cur = xg_a;
    float* xg_nxt = xg_b;
    __hip_bfloat16* m_cur = m_a;
    __hip_bfloat16* m_nxt = m_b;
    for (int i = 0; i < 3; ++i) {
        int hasNext = (i < 2) ? 1 : 0;
        k_step<<<nB_st, 256, 0, stream>>>(x, m_cur, m_nxt, batch, indptr, ssrc,
                                          wcat + OFF_Wa + i * 3072, xgw,
                                          wcat + OFF_Wg + i * 32, wcat + OFF_bg + i,
                                          wcat + OFF_Wa1, wcat + OFF_ba1,
                                          wcat + OFF_Wf + i * 1024, wcat + OFF_bf + i * 32,
                                          wcat + OFF_Wm + (i + 1) * 1024,
                                          wcat + OFF_bm + (i + 1) * 32,
                                          la1, U, S, N, hasNext);
        k_gupd<<<GG, 256, 0, stream>>>(U, S, xg_cur,
                                       wcat + OFF_Wt + i * 2048,
                                       wcat + OFF_bt + i * 32, xg_nxt,
                                       wcat + OFF_Wa + (i + 1) * 3072,
                                       wcat + OFF_ba + (i + 1) * 32,
                                       xgw, hasNext,
                                       la1, goff, W_v, b_v, W_a0, b_a0,
                                       d_out, N, dtf);
        float* tmp = xg_cur; xg_cur = xg_nxt; xg_nxt = tmp;
        __hip_bfloat16* tm = m_cur; m_cur = m_nxt; m_nxt = tm;
    }
}